// Round 14
// baseline (724.981 us; speedup 1.0000x reference)
//
#include <hip/hip_runtime.h>
#include <hip/hip_bf16.h>

// MHSA: B=16, C=256, H=W=48, N=2304.
// S[b,n,m] = q[b,:,n]·k[b,:,m] + rhq[b][n%48][m] + rwq[b][n/48][m]
// att = softmax_m(S); out[b,c,n] = sum_m v[b,c,m] att[n,m]
// Logits: f16 2-pass (qh·K + ql·K), K single f16 plane (R12-proven, 0.031).
// Split-KV (R13-proven): grid.z m-chunks write unnormalized partials + combine.
//
// R14: fat-phase schedule. R13's 4 sub-phases/tile = 5 barrier-drains/tile,
// each exposing stage latency after only ~16 MFMAs of cover. Now: stage the
// ENTIRE next tile (K 64x256 f16 + V 256x64 bf16, both double-buffered) at
// tile start, compute full S (64 MFMAs, 32 LDS reads) before the first
// barrier -> latency covered by intrinsic __syncthreads only (R9: asm regresses).
// 2 barriers/tile. LDS 145KB -> 1 blk/CU; 1152 split blocks self-balance.

#define BB 16
#define CC 256
#define HH 48
#define NN 2304

typedef float f32x4 __attribute__((ext_vector_type(4)));
typedef short bf16x8 __attribute__((ext_vector_type(8)));
typedef _Float16 f16x8 __attribute__((ext_vector_type(8)));

#define MFMA(a, b, c)  __builtin_amdgcn_mfma_f32_16x16x32_bf16((a), (b), (c), 0, 0, 0)
#define MFMAH(a, b, c) __builtin_amdgcn_mfma_f32_16x16x32_f16((a), (b), (c), 0, 0, 0)

__device__ inline bf16x8 ldg8(const __hip_bfloat16* p) {
    return *reinterpret_cast<const bf16x8*>(p);
}
__device__ inline f16x8 ldh8(const _Float16* p) {
    return *reinterpret_cast<const f16x8*>(p);
}
__device__ inline float bf2f(unsigned short v) {
    unsigned u = (unsigned)v << 16;
    float f;
    __builtin_memcpy(&f, &u, 4);
    return f;
}

typedef __attribute__((address_space(3))) unsigned int lds_uint;
typedef const __attribute__((address_space(1))) unsigned int gbl_uint;

__device__ inline void gload_lds16(const void* g, void* l) {
    __builtin_amdgcn_global_load_lds((gbl_uint*)g, (lds_uint*)l, 16, 0, 0);
}

// ---- prep: transpose x [b][c][n] -> xT [b][n][c], split into bf16 hi/lo ----
__global__ __launch_bounds__(256) void k_prep_x(const float* __restrict__ x,
        __hip_bfloat16* __restrict__ xt_hi, __hip_bfloat16* __restrict__ xt_lo) {
    __shared__ float tile[64][65];
    int b = blockIdx.z, n0 = blockIdx.x * 64, c0 = blockIdx.y * 64;
    const float* xb = x + (size_t)b * CC * NN;
    #pragma unroll
    for (int i = 0; i < 16; ++i) {
        int idx = i * 256 + threadIdx.x;
        int r = idx >> 6, col = idx & 63;
        tile[r][col] = xb[(size_t)(c0 + r) * NN + n0 + col];
    }
    __syncthreads();
    #pragma unroll
    for (int i = 0; i < 16; ++i) {
        int idx = i * 256 + threadIdx.x;
        int r = idx >> 6, col = idx & 63;           // r = n-local, col = c-local
        float v = tile[col][r];
        __hip_bfloat16 h = __float2bfloat16(v);
        size_t o = ((size_t)b * NN + n0 + r) * CC + c0 + col;
        xt_hi[o] = h;
        xt_lo[o] = __float2bfloat16(v - __bfloat162float(h));
    }
}

// ---- prep: split Wq/Wk/Wv into hi/lo (layout [3][256][256] row-major) ----
__global__ __launch_bounds__(256) void k_prep_w(const float* __restrict__ Wq,
        const float* __restrict__ Wk, const float* __restrict__ Wv,
        __hip_bfloat16* __restrict__ w_hi, __hip_bfloat16* __restrict__ w_lo) {
    int i = blockIdx.x * 256 + threadIdx.x;         // < 3*65536
    int m = i >> 16, j = i & 65535;
    const float* W = (m == 0) ? Wq : ((m == 1) ? Wk : Wv);
    float v = W[j];
    __hip_bfloat16 h = __float2bfloat16(v);
    w_hi[i] = h;
    w_lo[i] = __float2bfloat16(v - __bfloat162float(h));
}

// ---- prep: relhT[h][c] = rel_h[c][h] etc, f16 hi/lo split ----
__global__ __launch_bounds__(256) void k_prep_rel(const float* __restrict__ rel_h,
        const float* __restrict__ rel_w,
        _Float16* __restrict__ relhT_hi, _Float16* __restrict__ relhT_lo,
        _Float16* __restrict__ relwT_hi, _Float16* __restrict__ relwT_lo) {
    int i = blockIdx.x * 256 + threadIdx.x;         // < 48*256
    int h = i >> 8, c = i & 255;
    float vh = rel_h[c * HH + h];
    float vw = rel_w[c * HH + h];
    _Float16 hh = (_Float16)vh;
    relhT_hi[i] = hh;
    relhT_lo[i] = (_Float16)(vh - (float)hh);
    _Float16 hw = (_Float16)vw;
    relwT_hi[i] = hw;
    relwT_lo[i] = (_Float16)(vw - (float)hw);
}

// ---- projection GEMM: yT[b][n][o] = sum_c xT[b][n][c] * W[o][c] + bias[o] ----
// pj=0 -> qT f16 hi/lo, pj=1 -> kT f16 single, pj=2 -> v[b][o][n] bf16
__global__ __launch_bounds__(256) void k_proj(
        const __hip_bfloat16* __restrict__ xt_hi, const __hip_bfloat16* __restrict__ xt_lo,
        const __hip_bfloat16* __restrict__ w_hi,  const __hip_bfloat16* __restrict__ w_lo,
        const float* __restrict__ bq, const float* __restrict__ bk, const float* __restrict__ bv,
        _Float16* __restrict__ qt_hi, _Float16* __restrict__ qt_lo,
        _Float16* __restrict__ kt,
        __hip_bfloat16* __restrict__ vbuf) {
    int b = blockIdx.y, pj = blockIdx.z;
    int n0 = (blockIdx.x >> 2) * 64, o0 = (blockIdx.x & 3) * 64;
    int wave = threadIdx.x >> 6, lane = threadIdx.x & 63;
    int lr = lane & 15, lg = lane >> 4;
    int rowA = n0 + wave * 16 + lr;
    const __hip_bfloat16* wh = w_hi + (size_t)pj * 65536;
    const __hip_bfloat16* wl = w_lo + (size_t)pj * 65536;
    const __hip_bfloat16* axh = xt_hi + ((size_t)b * NN + rowA) * CC;
    const __hip_bfloat16* axl = xt_lo + ((size_t)b * NN + rowA) * CC;
    f32x4 acc[4] = {};
    #pragma unroll
    for (int ks = 0; ks < 8; ++ks) {
        int kk = ks * 32 + lg * 8;
        bf16x8 ah = ldg8(axh + kk);
        bf16x8 al = ldg8(axl + kk);
        #pragma unroll
        for (int ot = 0; ot < 4; ++ot) {
            int rowB = o0 + ot * 16 + lr;
            bf16x8 bh = ldg8(wh + rowB * CC + kk);
            bf16x8 bl = ldg8(wl + rowB * CC + kk);
            acc[ot] = MFMA(ah, bh, acc[ot]);
            acc[ot] = MFMA(ah, bl, acc[ot]);
            acc[ot] = MFMA(al, bh, acc[ot]);
        }
    }
    const float* bias = (pj == 0) ? bq : ((pj == 1) ? bk : bv);
    #pragma unroll
    for (int ot = 0; ot < 4; ++ot) {
        int o = o0 + ot * 16 + lr;
        float bb = bias[o];
        #pragma unroll
        for (int r = 0; r < 4; ++r) {
            int n = n0 + wave * 16 + lg * 4 + r;
            float y = acc[ot][r] + bb;
            if (pj == 0) {
                _Float16 h = (_Float16)y;
                size_t off = ((size_t)b * NN + n) * CC + o;
                qt_hi[off] = h;
                qt_lo[off] = (_Float16)(y - (float)h);
            } else if (pj == 1) {
                kt[((size_t)b * NN + n) * CC + o] = (_Float16)y;
            } else {
                vbuf[((size_t)b * CC + o) * NN + n] = __float2bfloat16(y);
            }
        }
    }
}

// ---- pos rank-split (f16 3-pass): rhq[b][h][m] = sum_c relhT[h][c] q[b][c][m]
__global__ __launch_bounds__(256) void k_posq(
        const _Float16* __restrict__ qt_hi, const _Float16* __restrict__ qt_lo,
        const _Float16* __restrict__ relhT_hi, const _Float16* __restrict__ relhT_lo,
        const _Float16* __restrict__ relwT_hi, const _Float16* __restrict__ relwT_lo,
        float* __restrict__ rhq, float* __restrict__ rwq) {
    int b = blockIdx.y, m0 = blockIdx.x * 64;
    int wave = threadIdx.x >> 6, lane = threadIdx.x & 63;
    int lr = lane & 15, lg = lane >> 4;
    int m = m0 + wave * 16 + lr;                    // output column
    const size_t bN = (size_t)b * NN;
    f32x4 acc[6] = {};                              // 3 h-tiles rh, 3 w-tiles rw
    #pragma unroll
    for (int ks = 0; ks < 8; ++ks) {
        int kk = ks * 32 + lg * 8;
        f16x8 bhf = ldh8(qt_hi + (bN + m) * CC + kk);
        f16x8 blf = ldh8(qt_lo + (bN + m) * CC + kk);
        #pragma unroll
        for (int t = 0; t < 3; ++t) {
            int rowH = t * 16 + lr;
            f16x8 ahh = ldh8(relhT_hi + rowH * CC + kk);
            f16x8 ahl = ldh8(relhT_lo + rowH * CC + kk);
            acc[t] = MFMAH(ahh, bhf, acc[t]);
            acc[t] = MFMAH(ahl, bhf, acc[t]);
            acc[t] = MFMAH(ahh, blf, acc[t]);
            f16x8 awh = ldh8(relwT_hi + rowH * CC + kk);
            f16x8 awl = ldh8(relwT_lo + rowH * CC + kk);
            acc[3 + t] = MFMAH(awh, bhf, acc[3 + t]);
            acc[3 + t] = MFMAH(awl, bhf, acc[3 + t]);
            acc[3 + t] = MFMAH(awh, blf, acc[3 + t]);
        }
    }
    #pragma unroll
    for (int t = 0; t < 3; ++t) {
        #pragma unroll
        for (int r = 0; r < 4; ++r) {
            int h = t * 16 + lg * 4 + r;
            rhq[((size_t)b * HH + h) * NN + m] = acc[t][r];
            rwq[((size_t)b * HH + h) * NN + m] = acc[3 + t][r];
        }
    }
}

// ---- flash attention, split-KV, fat-phase: block = 128 q-rows x tpb m-tiles --
// Per tile: stage next K(64x256 f16)+V(256x64 bf16) into buf^1, full S from
// buf (64 MFMAs), softmax, P->LDS, barrier, PV from buf, barrier. 2 barriers.
__global__ __launch_bounds__(512, 1) void k_attn(
        const _Float16* __restrict__ qt_hi, const _Float16* __restrict__ qt_lo,
        const _Float16* __restrict__ kt,
        const float* __restrict__ rhq, const float* __restrict__ rwq,
        const __hip_bfloat16* __restrict__ vbuf,
        __hip_bfloat16* __restrict__ o0, __hip_bfloat16* __restrict__ o1,
        __hip_bfloat16* __restrict__ o2, __hip_bfloat16* __restrict__ o3,
        float2* __restrict__ ml, int tpb) {
    __shared__ __align__(16) _Float16 lds_k[2][64][256];          // 64KB dbuf
    __shared__ __align__(16) __hip_bfloat16 lds_v[2][256][64];    // 64KB dbuf
    __shared__ __align__(16) __hip_bfloat16 lds_p[128][64];       // 16KB (swizzled)
    __shared__ float lds_scale[128];
    __shared__ float lds_lrun[128];
    int b = blockIdx.y;
    int n0 = blockIdx.x * 128;
    int z = blockIdx.z;
    int t0 = z * tpb, t_end = t0 + tpb;
    __hip_bfloat16* opart = (z == 0) ? o0 : (z == 1) ? o1 : (z == 2) ? o2 : o3;
    int wave = threadIdx.x >> 6, lane = threadIdx.x & 63;
    int lr = lane & 15, lg = lane >> 4;
    int rowA = n0 + wave * 16 + lr;
    const size_t bN = (size_t)b * NN;

    // Q fragments in registers: 16 rows x 256 k per wave, f16 hi+lo
    f16x8 qh[8], ql[8];
    #pragma unroll
    for (int ks = 0; ks < 8; ++ks) {
        int kk = ks * 32 + lg * 8;
        qh[ks] = ldh8(qt_hi + (bN + rowA) * CC + kk);
        ql[ks] = ldh8(qt_lo + (bN + rowA) * CC + kk);
    }
    // pos-table row indices for this lane's 4 softmax rows
    int hn[4], wn[4];
    #pragma unroll
    for (int r = 0; r < 4; ++r) {
        int n = n0 + wave * 16 + lg * 4 + r;
        hn[r] = n % HH;
        wn[r] = n / HH;
    }
    const float* rhq_b = rhq + (size_t)b * HH * NN;
    const float* rwq_b = rwq + (size_t)b * HH * NN;

    // PV ownership: [64n x 64c] per wave
    int nh = wave >> 2;                 // n-half
    int cq = wave & 3;                  // c-quarter
    f32x4 oacc[4][4] = {};              // [nf][cf]
    float mrun[4] = {-1e30f, -1e30f, -1e30f, -1e30f};
    float lrun[4] = {0.f, 0.f, 0.f, 0.f};

    // full-tile staging, XOR-swizzled source (both-sides with swizzled reads).
    // K: wave stages rows 8w..8w+7 (4 calls x 2 rows); lane r_in=lane>>5,
    // chunk=lane&31 (16B chunks, 32/row). V: rows 32w..32w+31 (4 calls x 8);
    // r_in=lane>>3, chunk=lane&7 (8 chunks/row).
    auto STAGE_K = [&](int buf, int m0s) {
        int r_in = lane >> 5, chunk = lane & 31;
        #pragma unroll
        for (int j = 0; j < 4; ++j) {
            int lrow = wave * 8 + 2 * j;
            int grow = lrow + r_in;                  // local == (global - m0s)
            gload_lds16(kt + (bN + m0s + grow) * CC + ((chunk ^ (grow & 7)) * 8),
                        &lds_k[buf][lrow][0]);
        }
    };
    auto STAGE_V = [&](int buf, int m0s) {
        int r_in = lane >> 3, chunk = lane & 7;
        #pragma unroll
        for (int j = 0; j < 4; ++j) {
            int lrow = wave * 32 + 8 * j;
            int crow = lrow + r_in;
            gload_lds16(vbuf + ((size_t)b * CC + crow) * NN + m0s + ((chunk ^ (crow & 7)) * 8),
                        &lds_v[buf][lrow][0]);
        }
    };

    int cur = 0;
    STAGE_K(0, t0 * 64);
    STAGE_V(0, t0 * 64);
    __syncthreads();

    for (int t = t0; t < t_end; ++t) {
        int m0 = t * 64;
        // stage next tile into buf^1 (last iter: restage t0 — unused, harmless)
        int mn = (t + 1 < t_end) ? (t + 1) * 64 : t0 * 64;
        STAGE_K(cur ^ 1, mn);
        STAGE_V(cur ^ 1, mn);
        // pos adds (global, consumed after S — hidden under MFMAs)
        float padd[4][4];
        #pragma unroll
        for (int mt = 0; mt < 4; ++mt) {
            int m = m0 + mt * 16 + lr;
            #pragma unroll
            for (int r = 0; r < 4; ++r)
                padd[mt][r] = rhq_b[(size_t)hn[r] * NN + m] + rwq_b[(size_t)wn[r] * NN + m];
        }
        // ---- S tile [16n x 64m], full K=256, f16 2-pass, no mid barriers ----
        f32x4 sacc[4] = {};
        #pragma unroll
        for (int ks = 0; ks < 8; ++ks) {
            #pragma unroll
            for (int mt = 0; mt < 4; ++mt) {
                int row = mt * 16 + lr;
                int ch = ((ks * 4 + lg) ^ (lr & 7)) * 8;       // swizzled read
                f16x8 bh = *reinterpret_cast<const f16x8*>(&lds_k[cur][row][ch]);
                sacc[mt] = MFMAH(qh[ks], bh, sacc[mt]);
                sacc[mt] = MFMAH(ql[ks], bh, sacc[mt]);
            }
        }
        // ---- add pos term, online softmax (per S-wave rows) ----
        #pragma unroll
        for (int mt = 0; mt < 4; ++mt)
            #pragma unroll
            for (int r = 0; r < 4; ++r)
                sacc[mt][r] += padd[mt][r];
        float scl_r[4];
        #pragma unroll
        for (int r = 0; r < 4; ++r) {
            float smax = fmaxf(fmaxf(sacc[0][r], sacc[1][r]), fmaxf(sacc[2][r], sacc[3][r]));
            #pragma unroll
            for (int mk = 1; mk <= 8; mk <<= 1)
                smax = fmaxf(smax, __shfl_xor(smax, mk));
            float mnew = fmaxf(mrun[r], smax);
            scl_r[r] = __expf(mrun[r] - mnew);
            float rsum = 0.f;
            #pragma unroll
            for (int mt = 0; mt < 4; ++mt) {
                float p = __expf(sacc[mt][r] - mnew);
                sacc[mt][r] = p;
                rsum += p;
            }
            #pragma unroll
            for (int mk = 1; mk <= 8; mk <<= 1)
                rsum += __shfl_xor(rsum, mk);
            lrun[r] = lrun[r] * scl_r[r] + rsum;
            mrun[r] = mnew;
        }
        // ---- P + scale -> shared LDS (XOR-swizzled P) ----
        #pragma unroll
        for (int mt = 0; mt < 4; ++mt) {
            #pragma unroll
            for (int r = 0; r < 4; ++r) {
                int prow = wave * 16 + lg * 4 + r;
                int pcol = mt * 16 + lr;
                int pcol_s = (((pcol >> 3) ^ (prow & 7)) << 3) | (pcol & 7);
                lds_p[prow][pcol_s] = __float2bfloat16(sacc[mt][r]);
            }
        }
        if (lr == 0) {
            #pragma unroll
            for (int r = 0; r < 4; ++r)
                lds_scale[wave * 16 + lg * 4 + r] = scl_r[r];
        }
        __syncthreads();   // barrier 1: P+scale visible (stage loads long since covered)
        // ---- PV: wave computes [64n x 64c]; rescale then accumulate ----
        f32x4 scl4[4];
        #pragma unroll
        for (int nf = 0; nf < 4; ++nf) {
            scl4[nf] = *reinterpret_cast<const f32x4*>(&lds_scale[nh * 64 + nf * 16 + lg * 4]);
            #pragma unroll
            for (int cf = 0; cf < 4; ++cf)
                oacc[nf][cf] *= scl4[nf];
        }
        #pragma unroll
        for (int ks2 = 0; ks2 < 2; ++ks2) {
            bf16x8 pa[4];
            #pragma unroll
            for (int nf = 0; nf < 4; ++nf) {
                int prow = nh * 64 + nf * 16 + lr;
                int pch = ((ks2 * 4 + lg) ^ (lr & 7)) * 8;
                pa[nf] = *reinterpret_cast<const bf16x8*>(&lds_p[prow][pch]);
            }
            #pragma unroll
            for (int cf = 0; cf < 4; ++cf) {
                int vrow = cq * 64 + cf * 16 + lr;
                int vch = ((ks2 * 4 + lg) ^ (lr & 7)) * 8;
                bf16x8 bv = *reinterpret_cast<const bf16x8*>(&lds_v[cur][vrow][vch]);
                #pragma unroll
                for (int nf = 0; nf < 4; ++nf)
                    oacc[nf][cf] = MFMA(pa[nf], bv, oacc[nf][cf]);
            }
        }
        __syncthreads();   // barrier 2: PV reads done before next P-write; next bufs landed
        cur ^= 1;
    }
    // ---- epilogue: store unnormalized partial o (bf16) and per-row (m,l) ----
    if (lr == 0) {
        #pragma unroll
        for (int r = 0; r < 4; ++r) {
            int n = n0 + wave * 16 + lg * 4 + r;
            ml[((size_t)z * BB + b) * NN + n] = make_float2(mrun[r], lrun[r]);
        }
    }
    #pragma unroll
    for (int nf = 0; nf < 4; ++nf) {
        int nbase = n0 + nh * 64 + nf * 16 + lg * 4;
        #pragma unroll
        for (int cf = 0; cf < 4; ++cf) {
            int c = cq * 64 + cf * 16 + lr;
            union { ushort4 u4; unsigned short us[4]; } pk;
            #pragma unroll
            for (int j = 0; j < 4; ++j) {
                __hip_bfloat16 hv = __float2bfloat16(oacc[nf][cf][j]);
                pk.us[j] = *reinterpret_cast<unsigned short*>(&hv);
            }
            *reinterpret_cast<ushort4*>(&opart[((size_t)b * CC + c) * NN + nbase]) = pk.u4;
        }
    }
}

// ---- combine: out[b][c][n] = sum_z o_z*exp(m_z-M) / sum_z l_z*exp(m_z-M) ----
__global__ __launch_bounds__(256) void k_combine(
        const __hip_bfloat16* __restrict__ o0, const __hip_bfloat16* __restrict__ o1,
        const __hip_bfloat16* __restrict__ o2, const __hip_bfloat16* __restrict__ o3,
        const float2* __restrict__ ml, int nsplit, float* __restrict__ out) {
    size_t idx = ((size_t)blockIdx.x * 256 + threadIdx.x) * 4;   // over B*CC*NN
    int n4 = (int)(idx % NN);
    int c  = (int)((idx / NN) % CC);
    int b  = (int)(idx / ((size_t)NN * CC));
    float M[4] = {-1e30f, -1e30f, -1e30f, -1e30f};
    for (int zz = 0; zz < nsplit; ++zz) {
        #pragma unroll
        for (int j = 0; j < 4; ++j)
            M[j] = fmaxf(M[j], ml[((size_t)zz * BB + b) * NN + n4 + j].x);
    }
    float num[4] = {}, den[4] = {};
    for (int zz = 0; zz < nsplit; ++zz) {
        const __hip_bfloat16* op = (zz == 0) ? o0 : (zz == 1) ? o1 : (zz == 2) ? o2 : o3;
        ushort4 u = *reinterpret_cast<const ushort4*>(op + ((size_t)b * CC + c) * NN + n4);
        unsigned short us[4] = {u.x, u.y, u.z, u.w};
        #pragma unroll
        for (int j = 0; j < 4; ++j) {
            float2 v = ml[((size_t)zz * BB + b) * NN + n4 + j];
            float w = __expf(v.x - M[j]);
            num[j] += bf2f(us[j]) * w;
            den[j] += v.y * w;
        }
    }
    f32x4 o;
    #pragma unroll
    for (int j = 0; j < 4; ++j) o[j] = num[j] / den[j];
    *reinterpret_cast<f32x4*>(&out[idx]) = o;
}

extern "C" void kernel_launch(void* const* d_in, const int* in_sizes, int n_in,
                              void* d_out, int out_size, void* d_ws, size_t ws_size,
                              hipStream_t stream) {
    const float* x     = (const float*)d_in[0];
    const float* Wq    = (const float*)d_in[1];
    const float* bq    = (const float*)d_in[2];
    const float* Wk    = (const float*)d_in[3];
    const float* bk    = (const float*)d_in[4];
    const float* Wv    = (const float*)d_in[5];
    const float* bv    = (const float*)d_in[6];
    const float* rel_h = (const float*)d_in[7];
    const float* rel_w = (const float*)d_in[8];
    float* out = (float*)d_out;

    size_t off = 0;
    auto carve = [&](size_t bytes) {
        void* p = (char*)d_ws + off;
        off += (bytes + 255) & ~(size_t)255;
        return p;
    };
    const size_t sz_t = (size_t)BB * NN * CC * 2;   // one 2B plane = 18.87 MB
    __hip_bfloat16* xt_hi  = (__hip_bfloat16*)carve(sz_t);
    __hip_bfloat16* xt_lo  = (__hip_bfloat16*)carve(sz_t);
    _Float16*       qt_hi  = (_Float16*)carve(sz_t);
    _Float16*       qt_lo  = (_Float16*)carve(sz_t);
    _Float16*       kt     = (_Float16*)carve(sz_t);
    __hip_bfloat16* vbuf   = (__hip_bfloat16*)carve(sz_t);
    _Float16* relhT_hi = (_Float16*)carve((size_t)HH * CC * 2);
    _Float16* relhT_lo = (_Float16*)carve((size_t)HH * CC * 2);
    _Float16* relwT_hi = (_Float16*)carve((size_t)HH * CC * 2);
    _Float16* relwT_lo = (_Float16*)carve((size_t)HH * CC * 2);
    __hip_bfloat16* w_hi   = (__hip_bfloat16*)carve((size_t)3 * CC * CC * 2);
    __hip_bfloat16* w_lo   = (__hip_bfloat16*)carve((size_t)3 * CC * CC * 2);
    float* rhq = (float*)carve((size_t)BB * HH * NN * 4);
    float* rwq = (float*)carve((size_t)BB * HH * NN * 4);
    float2* ml = (float2*)carve((size_t)4 * BB * NN * sizeof(float2));
    if (off > ws_size) return;   // base workspace too small -> visible failure

    // split-KV partial planes: 0/1 alias dead xt_hi/xt_lo; 2/3 only if ws fits
    __hip_bfloat16* o0 = xt_hi;
    __hip_bfloat16* o1 = xt_lo;
    __hip_bfloat16* o2 = nullptr;
    __hip_bfloat16* o3 = nullptr;
    int nsplit = 2;
    {
        size_t save = off;
        __hip_bfloat16* p2 = (__hip_bfloat16*)carve(sz_t);
        __hip_bfloat16* p3 = (__hip_bfloat16*)carve(sz_t);
        if (off <= ws_size) { nsplit = 4; o2 = p2; o3 = p3; }
        else { off = save; }
    }
    int tpb = 36 / nsplit;

    k_prep_x<<<dim3(NN / 64, CC / 64, BB), 256, 0, stream>>>(x, xt_hi, xt_lo);
    k_prep_w<<<dim3(3 * CC * CC / 256), 256, 0, stream>>>(Wq, Wk, Wv, w_hi, w_lo);
    k_prep_rel<<<dim3(HH * CC / 256), 256, 0, stream>>>(rel_h, rel_w,
        relhT_hi, relhT_lo, relwT_hi, relwT_lo);
    k_proj<<<dim3((NN / 64) * (CC / 64), BB, 3), 256, 0, stream>>>(
        xt_hi, xt_lo, w_hi, w_lo, bq, bk, bv, qt_hi, qt_lo, kt, vbuf);
    k_posq<<<dim3(NN / 64, BB), 256, 0, stream>>>(
        qt_hi, qt_lo, relhT_hi, relhT_lo, relwT_hi, relwT_lo, rhq, rwq);
    k_attn<<<dim3(NN / 128, BB, nsplit), 512, 0, stream>>>(
        qt_hi, qt_lo, kt, rhq, rwq, vbuf, o0, o1, o2, o3, ml, tpb);
    k_combine<<<dim3((size_t)BB * CC * NN / 1024), 256, 0, stream>>>(
        o0, o1, o2, o3, ml, nsplit, out);
}

// Round 15
// 578.305 us; speedup vs baseline: 1.2536x; 1.2536x over previous
//
#include <hip/hip_runtime.h>
#include <hip/hip_bf16.h>

// MHSA: B=16, C=256, H=W=48, N=2304.
// S[b,n,m] = q[b,:,n]·k[b,:,m] + rhq[b][n%48][m] + rwq[b][n/48][m]
// att = softmax_m(S); out[b,c,n] = sum_m v[b,c,m] att[n,m]
// Logits: f16 2-pass (qh·K + ql·K), K single f16 plane (R12-proven, 0.031).
// Split-KV (R13-proven, 318us): grid.z m-chunks -> partials + combine.
//
// R14 lesson: fat-phase (whole-tile staging, 1 blk/CU) regressed 318->359
// and created 1e7 bank conflicts (DMA-burst vs ds_read port contention) —
// attn reverted to R13 verbatim. R15: side pipeline (~285us > attn!) —
// k_proj rewritten with R6-proven LDS staging: A-tile (xT 32 rows, hi+lo)
// staged once per block (XOR pre-swizzle), shared by 4 o-slice waves;
// 1 barrier/block; 4x less A traffic; blocks 6912 -> 1728.

#define BB 16
#define CC 256
#define HH 48
#define NN 2304

typedef float f32x4 __attribute__((ext_vector_type(4)));
typedef short bf16x8 __attribute__((ext_vector_type(8)));
typedef _Float16 f16x8 __attribute__((ext_vector_type(8)));

#define MFMA(a, b, c)  __builtin_amdgcn_mfma_f32_16x16x32_bf16((a), (b), (c), 0, 0, 0)
#define MFMAH(a, b, c) __builtin_amdgcn_mfma_f32_16x16x32_f16((a), (b), (c), 0, 0, 0)

__device__ inline bf16x8 ldg8(const __hip_bfloat16* p) {
    return *reinterpret_cast<const bf16x8*>(p);
}
__device__ inline f16x8 ldh8(const _Float16* p) {
    return *reinterpret_cast<const f16x8*>(p);
}
__device__ inline float bf2f(unsigned short v) {
    unsigned u = (unsigned)v << 16;
    float f;
    __builtin_memcpy(&f, &u, 4);
    return f;
}

typedef __attribute__((address_space(3))) unsigned int lds_uint;
typedef const __attribute__((address_space(1))) unsigned int gbl_uint;

__device__ inline void gload_lds16(const void* g, void* l) {
    __builtin_amdgcn_global_load_lds((gbl_uint*)g, (lds_uint*)l, 16, 0, 0);
}

// ---- prep: transpose x [b][c][n] -> xT [b][n][c], split into bf16 hi/lo ----
__global__ __launch_bounds__(256) void k_prep_x(const float* __restrict__ x,
        __hip_bfloat16* __restrict__ xt_hi, __hip_bfloat16* __restrict__ xt_lo) {
    __shared__ float tile[64][65];
    int b = blockIdx.z, n0 = blockIdx.x * 64, c0 = blockIdx.y * 64;
    const float* xb = x + (size_t)b * CC * NN;
    #pragma unroll
    for (int i = 0; i < 16; ++i) {
        int idx = i * 256 + threadIdx.x;
        int r = idx >> 6, col = idx & 63;
        tile[r][col] = xb[(size_t)(c0 + r) * NN + n0 + col];
    }
    __syncthreads();
    #pragma unroll
    for (int i = 0; i < 16; ++i) {
        int idx = i * 256 + threadIdx.x;
        int r = idx >> 6, col = idx & 63;           // r = n-local, col = c-local
        float v = tile[col][r];
        __hip_bfloat16 h = __float2bfloat16(v);
        size_t o = ((size_t)b * NN + n0 + r) * CC + c0 + col;
        xt_hi[o] = h;
        xt_lo[o] = __float2bfloat16(v - __bfloat162float(h));
    }
}

// ---- prep: split Wq/Wk/Wv into hi/lo (layout [3][256][256] row-major) ----
__global__ __launch_bounds__(256) void k_prep_w(const float* __restrict__ Wq,
        const float* __restrict__ Wk, const float* __restrict__ Wv,
        __hip_bfloat16* __restrict__ w_hi, __hip_bfloat16* __restrict__ w_lo) {
    int i = blockIdx.x * 256 + threadIdx.x;         // < 3*65536
    int m = i >> 16, j = i & 65535;
    const float* W = (m == 0) ? Wq : ((m == 1) ? Wk : Wv);
    float v = W[j];
    __hip_bfloat16 h = __float2bfloat16(v);
    w_hi[i] = h;
    w_lo[i] = __float2bfloat16(v - __bfloat162float(h));
}

// ---- prep: relhT[h][c] = rel_h[c][h] etc, f16 hi/lo split ----
__global__ __launch_bounds__(256) void k_prep_rel(const float* __restrict__ rel_h,
        const float* __restrict__ rel_w,
        _Float16* __restrict__ relhT_hi, _Float16* __restrict__ relhT_lo,
        _Float16* __restrict__ relwT_hi, _Float16* __restrict__ relwT_lo) {
    int i = blockIdx.x * 256 + threadIdx.x;         // < 48*256
    int h = i >> 8, c = i & 255;
    float vh = rel_h[c * HH + h];
    float vw = rel_w[c * HH + h];
    _Float16 hh = (_Float16)vh;
    relhT_hi[i] = hh;
    relhT_lo[i] = (_Float16)(vh - (float)hh);
    _Float16 hw = (_Float16)vw;
    relwT_hi[i] = hw;
    relwT_lo[i] = (_Float16)(vw - (float)hw);
}

// ---- projection GEMM, LDS-staged A (R15) ----
// grid (72, 16, 3); block = 32 n-rows x 256 o-cols, 4 waves (o-slice each).
// A-tile xT[n0:n0+32][0:256] hi+lo staged ONCE in LDS (XOR pre-swizzled
// source, swizzled reads — both-sides, R6-proven). W from global (L2-hot).
// pj=0 -> qT f16 hi/lo, pj=1 -> kT f16 single, pj=2 -> v[b][o][n] bf16
__global__ __launch_bounds__(256) void k_proj(
        const __hip_bfloat16* __restrict__ xt_hi, const __hip_bfloat16* __restrict__ xt_lo,
        const __hip_bfloat16* __restrict__ w_hi,  const __hip_bfloat16* __restrict__ w_lo,
        const float* __restrict__ bq, const float* __restrict__ bk, const float* __restrict__ bv,
        _Float16* __restrict__ qt_hi, _Float16* __restrict__ qt_lo,
        _Float16* __restrict__ kt,
        __hip_bfloat16* __restrict__ vbuf) {
    __shared__ __align__(16) __hip_bfloat16 lds_a[2][32][256];   // [hi/lo][row][c] 32KB
    int b = blockIdx.y, pj = blockIdx.z;
    int n0 = blockIdx.x * 32;
    int wave = threadIdx.x >> 6, lane = threadIdx.x & 63;
    int lr = lane & 15, lg = lane >> 4;
    int o0 = wave * 64;
    const size_t bN = (size_t)b * NN;
    const __hip_bfloat16* wh = w_hi + (size_t)pj * 65536;
    const __hip_bfloat16* wl = w_lo + (size_t)pj * 65536;

    // stage A: wave w stages rows w*8..w*8+7 of each plane (4 calls x 2 rows).
    // phys chunk c of row r holds logical chunk c^(r&7) (pre-swizzled source).
    {
        int r_in = lane >> 5, chunk = lane & 31;
        #pragma unroll
        for (int j = 0; j < 4; ++j) {
            int lrow = wave * 8 + 2 * j;
            int row = lrow + r_in;
            gload_lds16(xt_hi + (bN + n0 + row) * CC + ((chunk ^ (row & 7)) * 8),
                        &lds_a[0][lrow][0]);
            gload_lds16(xt_lo + (bN + n0 + row) * CC + ((chunk ^ (row & 7)) * 8),
                        &lds_a[1][lrow][0]);
        }
    }
    __syncthreads();

    f32x4 acc[2][4] = {};
    #pragma unroll
    for (int ks = 0; ks < 8; ++ks) {
        int kk = ks * 32 + lg * 8;
        bf16x8 ah[2], al[2];
        #pragma unroll
        for (int nt = 0; nt < 2; ++nt) {
            int row = nt * 16 + lr;
            int ch = ((ks * 4 + lg) ^ (lr & 7)) * 8;             // swizzled read
            ah[nt] = *reinterpret_cast<const bf16x8*>(&lds_a[0][row][ch]);
            al[nt] = *reinterpret_cast<const bf16x8*>(&lds_a[1][row][ch]);
        }
        #pragma unroll
        for (int ot = 0; ot < 4; ++ot) {
            int rowB = o0 + ot * 16 + lr;
            bf16x8 bh = ldg8(wh + rowB * CC + kk);
            bf16x8 bl = ldg8(wl + rowB * CC + kk);
            #pragma unroll
            for (int nt = 0; nt < 2; ++nt) {
                acc[nt][ot] = MFMA(ah[nt], bh, acc[nt][ot]);
                acc[nt][ot] = MFMA(ah[nt], bl, acc[nt][ot]);
                acc[nt][ot] = MFMA(al[nt], bh, acc[nt][ot]);
            }
        }
    }
    const float* bias = (pj == 0) ? bq : ((pj == 1) ? bk : bv);
    #pragma unroll
    for (int ot = 0; ot < 4; ++ot) {
        int o = o0 + ot * 16 + lr;
        float bb = bias[o];
        #pragma unroll
        for (int nt = 0; nt < 2; ++nt) {
            #pragma unroll
            for (int r = 0; r < 4; ++r) {
                int n = n0 + nt * 16 + lg * 4 + r;
                float y = acc[nt][ot][r] + bb;
                if (pj == 0) {
                    _Float16 h = (_Float16)y;
                    size_t off = (bN + n) * CC + o;
                    qt_hi[off] = h;
                    qt_lo[off] = (_Float16)(y - (float)h);
                } else if (pj == 1) {
                    kt[(bN + n) * CC + o] = (_Float16)y;
                } else {
                    vbuf[((size_t)b * CC + o) * NN + n] = __float2bfloat16(y);
                }
            }
        }
    }
}

// ---- pos rank-split (f16 3-pass): rhq[b][h][m] = sum_c relhT[h][c] q[b][c][m]
__global__ __launch_bounds__(256) void k_posq(
        const _Float16* __restrict__ qt_hi, const _Float16* __restrict__ qt_lo,
        const _Float16* __restrict__ relhT_hi, const _Float16* __restrict__ relhT_lo,
        const _Float16* __restrict__ relwT_hi, const _Float16* __restrict__ relwT_lo,
        float* __restrict__ rhq, float* __restrict__ rwq) {
    int b = blockIdx.y, m0 = blockIdx.x * 64;
    int wave = threadIdx.x >> 6, lane = threadIdx.x & 63;
    int lr = lane & 15, lg = lane >> 4;
    int m = m0 + wave * 16 + lr;                    // output column
    const size_t bN = (size_t)b * NN;
    f32x4 acc[6] = {};                              // 3 h-tiles rh, 3 w-tiles rw
    #pragma unroll
    for (int ks = 0; ks < 8; ++ks) {
        int kk = ks * 32 + lg * 8;
        f16x8 bhf = ldh8(qt_hi + (bN + m) * CC + kk);
        f16x8 blf = ldh8(qt_lo + (bN + m) * CC + kk);
        #pragma unroll
        for (int t = 0; t < 3; ++t) {
            int rowH = t * 16 + lr;
            f16x8 ahh = ldh8(relhT_hi + rowH * CC + kk);
            f16x8 ahl = ldh8(relhT_lo + rowH * CC + kk);
            acc[t] = MFMAH(ahh, bhf, acc[t]);
            acc[t] = MFMAH(ahl, bhf, acc[t]);
            acc[t] = MFMAH(ahh, blf, acc[t]);
            f16x8 awh = ldh8(relwT_hi + rowH * CC + kk);
            f16x8 awl = ldh8(relwT_lo + rowH * CC + kk);
            acc[3 + t] = MFMAH(awh, bhf, acc[3 + t]);
            acc[3 + t] = MFMAH(awl, bhf, acc[3 + t]);
            acc[3 + t] = MFMAH(awh, blf, acc[3 + t]);
        }
    }
    #pragma unroll
    for (int t = 0; t < 3; ++t) {
        #pragma unroll
        for (int r = 0; r < 4; ++r) {
            int h = t * 16 + lg * 4 + r;
            rhq[((size_t)b * HH + h) * NN + m] = acc[t][r];
            rwq[((size_t)b * HH + h) * NN + m] = acc[3 + t][r];
        }
    }
}

// ---- flash attention, split-KV (R13 verbatim): 128 q-rows x tpb m-tiles ----
__global__ __launch_bounds__(512, 2) void k_attn(
        const _Float16* __restrict__ qt_hi, const _Float16* __restrict__ qt_lo,
        const _Float16* __restrict__ kt,
        const float* __restrict__ rhq, const float* __restrict__ rwq,
        const __hip_bfloat16* __restrict__ vbuf,
        __hip_bfloat16* __restrict__ o0, __hip_bfloat16* __restrict__ o1,
        __hip_bfloat16* __restrict__ o2, __hip_bfloat16* __restrict__ o3,
        float2* __restrict__ ml, int tpb) {
    __shared__ __align__(16) _Float16 lds_k[2][64][64];           // [buf][row][k] 16KB
    __shared__ __align__(16) __hip_bfloat16 lds_v[256][64];       // [c][m] 32KB (swizzled)
    __shared__ __align__(16) __hip_bfloat16 lds_p[128][64];       // shared P tile 16KB (swizzled)
    float* lds_scale = reinterpret_cast<float*>(&lds_k[1][0][0]); // dead-buf alias (R11-proven)
    int b = blockIdx.y;
    int n0 = blockIdx.x * 128;
    int z = blockIdx.z;
    int t0 = z * tpb, t_end = t0 + tpb;
    __hip_bfloat16* opart = (z == 0) ? o0 : (z == 1) ? o1 : (z == 2) ? o2 : o3;
    int wave = threadIdx.x >> 6, lane = threadIdx.x & 63;
    int lr = lane & 15, lg = lane >> 4;
    int rowA = n0 + wave * 16 + lr;
    const size_t bN = (size_t)b * NN;

    f16x8 qh[8], ql[8];
    #pragma unroll
    for (int ks = 0; ks < 8; ++ks) {
        int kk = ks * 32 + lg * 8;
        qh[ks] = ldh8(qt_hi + (bN + rowA) * CC + kk);
        ql[ks] = ldh8(qt_lo + (bN + rowA) * CC + kk);
    }
    int hn[4], wn[4];
    #pragma unroll
    for (int r = 0; r < 4; ++r) {
        int n = n0 + wave * 16 + lg * 4 + r;
        hn[r] = n % HH;
        wn[r] = n / HH;
    }
    const float* rhq_b = rhq + (size_t)b * HH * NN;
    const float* rwq_b = rwq + (size_t)b * HH * NN;

    int nh = wave >> 2;                 // n-half
    int cq = wave & 3;                  // c-quarter
    f32x4 oacc[4][4] = {};              // [nf][cf]
    float mrun[4] = {-1e30f, -1e30f, -1e30f, -1e30f};
    float lrun[4] = {0.f, 0.f, 0.f, 0.f};

    int srl = lane >> 3;
    int sch = ((lane & 7) ^ srl) * 8;
    auto STAGE_K = [&](int buf, int m0s, int k0) {
        int grow = m0s + wave * 8 + srl;
        gload_lds16(kt + (bN + grow) * CC + k0 + sch, &lds_k[buf][wave * 8][0]);
    };
    auto STAGE_V = [&](int q, int m0s) {
        int crow = q * 64 + wave * 8 + srl;
        gload_lds16(vbuf + ((size_t)b * CC + crow) * NN + m0s + sch, &lds_v[q * 64 + wave * 8][0]);
    };

    int cur = 0;
    STAGE_K(0, t0 * 64, 0);
    __syncthreads();

    for (int t = t0; t < t_end; ++t) {
        int m0 = t * 64;
        float padd[4][4];
        #pragma unroll
        for (int mt = 0; mt < 4; ++mt) {
            int m = m0 + mt * 16 + lr;
            #pragma unroll
            for (int r = 0; r < 4; ++r)
                padd[mt][r] = rhq_b[(size_t)hn[r] * NN + m] + rwq_b[(size_t)wn[r] * NN + m];
        }
        f32x4 sacc[4] = {};
        #pragma unroll
        for (int ph = 0; ph < 4; ++ph) {
            if (ph < 3) STAGE_K(cur ^ 1, m0, (ph + 1) * 64);
            else if (t + 1 < t_end) STAGE_K(cur ^ 1, m0 + 64, 0);
            STAGE_V(ph, m0);
            #pragma unroll
            for (int ks = 0; ks < 2; ++ks) {
                #pragma unroll
                for (int mt = 0; mt < 4; ++mt) {
                    int row = mt * 16 + lr;
                    int ch = ((ks * 4 + lg) ^ (lr & 7)) * 8;
                    f16x8 bh = *reinterpret_cast<const f16x8*>(&lds_k[cur][row][ch]);
                    sacc[mt] = MFMAH(qh[ph * 2 + ks], bh, sacc[mt]);
                    sacc[mt] = MFMAH(ql[ph * 2 + ks], bh, sacc[mt]);
                }
            }
            __syncthreads();
            cur ^= 1;
        }
        #pragma unroll
        for (int mt = 0; mt < 4; ++mt)
            #pragma unroll
            for (int r = 0; r < 4; ++r)
                sacc[mt][r] += padd[mt][r];
        float scl_r[4];
        #pragma unroll
        for (int r = 0; r < 4; ++r) {
            float smax = fmaxf(fmaxf(sacc[0][r], sacc[1][r]), fmaxf(sacc[2][r], sacc[3][r]));
            #pragma unroll
            for (int mk = 1; mk <= 8; mk <<= 1)
                smax = fmaxf(smax, __shfl_xor(smax, mk));
            float mnew = fmaxf(mrun[r], smax);
            scl_r[r] = __expf(mrun[r] - mnew);
            float rsum = 0.f;
            #pragma unroll
            for (int mt = 0; mt < 4; ++mt) {
                float p = __expf(sacc[mt][r] - mnew);
                sacc[mt][r] = p;
                rsum += p;
            }
            #pragma unroll
            for (int mk = 1; mk <= 8; mk <<= 1)
                rsum += __shfl_xor(rsum, mk);
            lrun[r] = lrun[r] * scl_r[r] + rsum;
            mrun[r] = mnew;
        }
        #pragma unroll
        for (int mt = 0; mt < 4; ++mt) {
            #pragma unroll
            for (int r = 0; r < 4; ++r) {
                int prow = wave * 16 + lg * 4 + r;
                int pcol = mt * 16 + lr;
                int pcol_s = (((pcol >> 3) ^ (prow & 7)) << 3) | (pcol & 7);
                lds_p[prow][pcol_s] = __float2bfloat16(sacc[mt][r]);
            }
        }
        if (lr == 0) {
            #pragma unroll
            for (int r = 0; r < 4; ++r)
                lds_scale[wave * 16 + lg * 4 + r] = scl_r[r];
        }
        __syncthreads();
        f32x4 scl4[4];
        #pragma unroll
        for (int nf = 0; nf < 4; ++nf) {
            scl4[nf] = *reinterpret_cast<const f32x4*>(&lds_scale[nh * 64 + nf * 16 + lg * 4]);
            #pragma unroll
            for (int cf = 0; cf < 4; ++cf)
                oacc[nf][cf] *= scl4[nf];
        }
        #pragma unroll
        for (int ks2 = 0; ks2 < 2; ++ks2) {
            bf16x8 pa[4];
            #pragma unroll
            for (int nf = 0; nf < 4; ++nf) {
                int prow = nh * 64 + nf * 16 + lr;
                int pch = ((ks2 * 4 + lg) ^ (lr & 7)) * 8;
                pa[nf] = *reinterpret_cast<const bf16x8*>(&lds_p[prow][pch]);
            }
            #pragma unroll
            for (int cf = 0; cf < 4; ++cf) {
                int vrow = cq * 64 + cf * 16 + lr;
                int vch = ((ks2 * 4 + lg) ^ (lr & 7)) * 8;
                bf16x8 bv = *reinterpret_cast<const bf16x8*>(&lds_v[vrow][vch]);
                #pragma unroll
                for (int nf = 0; nf < 4; ++nf)
                    oacc[nf][cf] = MFMA(pa[nf], bv, oacc[nf][cf]);
            }
        }
        __syncthreads();
    }
    if (lr == 0) {
        #pragma unroll
        for (int r = 0; r < 4; ++r) {
            int n = n0 + wave * 16 + lg * 4 + r;
            ml[((size_t)z * BB + b) * NN + n] = make_float2(mrun[r], lrun[r]);
        }
    }
    #pragma unroll
    for (int nf = 0; nf < 4; ++nf) {
        int nbase = n0 + nh * 64 + nf * 16 + lg * 4;
        #pragma unroll
        for (int cf = 0; cf < 4; ++cf) {
            int c = cq * 64 + cf * 16 + lr;
            union { ushort4 u4; unsigned short us[4]; } pk;
            #pragma unroll
            for (int j = 0; j < 4; ++j) {
                __hip_bfloat16 hv = __float2bfloat16(oacc[nf][cf][j]);
                pk.us[j] = *reinterpret_cast<unsigned short*>(&hv);
            }
            *reinterpret_cast<ushort4*>(&opart[((size_t)b * CC + c) * NN + nbase]) = pk.u4;
        }
    }
}

// ---- combine: out[b][c][n] = sum_z o_z*exp(m_z-M) / sum_z l_z*exp(m_z-M) ----
__global__ __launch_bounds__(256) void k_combine(
        const __hip_bfloat16* __restrict__ o0, const __hip_bfloat16* __restrict__ o1,
        const __hip_bfloat16* __restrict__ o2, const __hip_bfloat16* __restrict__ o3,
        const float2* __restrict__ ml, int nsplit, float* __restrict__ out) {
    size_t idx = ((size_t)blockIdx.x * 256 + threadIdx.x) * 4;   // over B*CC*NN
    int n4 = (int)(idx % NN);
    int c  = (int)((idx / NN) % CC);
    int b  = (int)(idx / ((size_t)NN * CC));
    float M[4] = {-1e30f, -1e30f, -1e30f, -1e30f};
    for (int zz = 0; zz < nsplit; ++zz) {
        #pragma unroll
        for (int j = 0; j < 4; ++j)
            M[j] = fmaxf(M[j], ml[((size_t)zz * BB + b) * NN + n4 + j].x);
    }
    float num[4] = {}, den[4] = {};
    for (int zz = 0; zz < nsplit; ++zz) {
        const __hip_bfloat16* op = (zz == 0) ? o0 : (zz == 1) ? o1 : (zz == 2) ? o2 : o3;
        ushort4 u = *reinterpret_cast<const ushort4*>(op + ((size_t)b * CC + c) * NN + n4);
        unsigned short us[4] = {u.x, u.y, u.z, u.w};
        #pragma unroll
        for (int j = 0; j < 4; ++j) {
            float2 v = ml[((size_t)zz * BB + b) * NN + n4 + j];
            float w = __expf(v.x - M[j]);
            num[j] += bf2f(us[j]) * w;
            den[j] += v.y * w;
        }
    }
    f32x4 o;
    #pragma unroll
    for (int j = 0; j < 4; ++j) o[j] = num[j] / den[j];
    *reinterpret_cast<f32x4*>(&out[idx]) = o;
}

extern "C" void kernel_launch(void* const* d_in, const int* in_sizes, int n_in,
                              void* d_out, int out_size, void* d_ws, size_t ws_size,
                              hipStream_t stream) {
    const float* x     = (const float*)d_in[0];
    const float* Wq    = (const float*)d_in[1];
    const float* bq    = (const float*)d_in[2];
    const float* Wk    = (const float*)d_in[3];
    const float* bk    = (const float*)d_in[4];
    const float* Wv    = (const float*)d_in[5];
    const float* bv    = (const float*)d_in[6];
    const float* rel_h = (const float*)d_in[7];
    const float* rel_w = (const float*)d_in[8];
    float* out = (float*)d_out;

    size_t off = 0;
    auto carve = [&](size_t bytes) {
        void* p = (char*)d_ws + off;
        off += (bytes + 255) & ~(size_t)255;
        return p;
    };
    const size_t sz_t = (size_t)BB * NN * CC * 2;   // one 2B plane = 18.87 MB
    __hip_bfloat16* xt_hi  = (__hip_bfloat16*)carve(sz_t);
    __hip_bfloat16* xt_lo  = (__hip_bfloat16*)carve(sz_t);
    _Float16*       qt_hi  = (_Float16*)carve(sz_t);
    _Float16*       qt_lo  = (_Float16*)carve(sz_t);
    _Float16*       kt     = (_Float16*)carve(sz_t);
    __hip_bfloat16* vbuf   = (__hip_bfloat16*)carve(sz_t);
    _Float16* relhT_hi = (_Float16*)carve((size_t)HH * CC * 2);
    _Float16* relhT_lo = (_Float16*)carve((size_t)HH * CC * 2);
    _Float16* relwT_hi = (_Float16*)carve((size_t)HH * CC * 2);
    _Float16* relwT_lo = (_Float16*)carve((size_t)HH * CC * 2);
    __hip_bfloat16* w_hi   = (__hip_bfloat16*)carve((size_t)3 * CC * CC * 2);
    __hip_bfloat16* w_lo   = (__hip_bfloat16*)carve((size_t)3 * CC * CC * 2);
    float* rhq = (float*)carve((size_t)BB * HH * NN * 4);
    float* rwq = (float*)carve((size_t)BB * HH * NN * 4);
    float2* ml = (float2*)carve((size_t)4 * BB * NN * sizeof(float2));
    if (off > ws_size) return;   // base workspace too small -> visible failure

    // split-KV partial planes: 0/1 alias dead xt_hi/xt_lo; 2/3 only if ws fits
    __hip_bfloat16* o0 = xt_hi;
    __hip_bfloat16* o1 = xt_lo;
    __hip_bfloat16* o2 = nullptr;
    __hip_bfloat16* o3 = nullptr;
    int nsplit = 2;
    {
        size_t save = off;
        __hip_bfloat16* p2 = (__hip_bfloat16*)carve(sz_t);
        __hip_bfloat16* p3 = (__hip_bfloat16*)carve(sz_t);
        if (off <= ws_size) { nsplit = 4; o2 = p2; o3 = p3; }
        else { off = save; }
    }
    int tpb = 36 / nsplit;

    k_prep_x<<<dim3(NN / 64, CC / 64, BB), 256, 0, stream>>>(x, xt_hi, xt_lo);
    k_prep_w<<<dim3(3 * CC * CC / 256), 256, 0, stream>>>(Wq, Wk, Wv, w_hi, w_lo);
    k_prep_rel<<<dim3(HH * CC / 256), 256, 0, stream>>>(rel_h, rel_w,
        relhT_hi, relhT_lo, relwT_hi, relwT_lo);
    k_proj<<<dim3(NN / 32, BB, 3), 256, 0, stream>>>(
        xt_hi, xt_lo, w_hi, w_lo, bq, bk, bv, qt_hi, qt_lo, kt, vbuf);
    k_posq<<<dim3(NN / 64, BB), 256, 0, stream>>>(
        qt_hi, qt_lo, relhT_hi, relhT_lo, relwT_hi, relwT_lo, rhq, rwq);
    k_attn<<<dim3(NN / 128, BB, nsplit), 512, 0, stream>>>(
        qt_hi, qt_lo, kt, rhq, rwq, vbuf, o0, o1, o2, o3, ml, tpb);
    k_combine<<<dim3((size_t)BB * CC * NN / 1024), 256, 0, stream>>>(
        o0, o1, o2, o3, ml, nsplit, out);
}

// Round 16
// 528.610 us; speedup vs baseline: 1.3715x; 1.0940x over previous
//
#include <hip/hip_runtime.h>
#include <hip/hip_bf16.h>

// MHSA: B=16, C=256, H=W=48, N=2304.
// S[b,n,m] = q[b,:,n]·k[b,:,m] + rhq[b][n%48][m] + rwq[b][n/48][m]
// att = softmax_m(S); out[b,c,n] = sum_m v[b,c,m] att[n,m]
// Numerics (R16): all-f16 pipeline. W single f16 plane (2.4e-4 rel), x f16
// hi/lo. Proj: q,k 2-pass (xh·W + xl·W), v 1-pass. posq 2-pass (rel_hi only).
// Logit err ~8e-3 rms << softmax scale; budget 0.104.
// Attn: split-KV (R13) + K-slice 128 -> 2 S-phases, 4 barriers/tile (was 6).

#define BB 16
#define CC 256
#define HH 48
#define NN 2304

typedef float f32x4 __attribute__((ext_vector_type(4)));
typedef short bf16x8 __attribute__((ext_vector_type(8)));
typedef _Float16 f16x8 __attribute__((ext_vector_type(8)));

#define MFMA(a, b, c)  __builtin_amdgcn_mfma_f32_16x16x32_bf16((a), (b), (c), 0, 0, 0)
#define MFMAH(a, b, c) __builtin_amdgcn_mfma_f32_16x16x32_f16((a), (b), (c), 0, 0, 0)

__device__ inline bf16x8 ldg8(const __hip_bfloat16* p) {
    return *reinterpret_cast<const bf16x8*>(p);
}
__device__ inline f16x8 ldh8(const _Float16* p) {
    return *reinterpret_cast<const f16x8*>(p);
}
__device__ inline float bf2f(unsigned short v) {
    unsigned u = (unsigned)v << 16;
    float f;
    __builtin_memcpy(&f, &u, 4);
    return f;
}

typedef __attribute__((address_space(3))) unsigned int lds_uint;
typedef const __attribute__((address_space(1))) unsigned int gbl_uint;

__device__ inline void gload_lds16(const void* g, void* l) {
    __builtin_amdgcn_global_load_lds((gbl_uint*)g, (lds_uint*)l, 16, 0, 0);
}

// ---- prep: transpose x [b][c][n] -> xT [b][n][c], split into f16 hi/lo ----
__global__ __launch_bounds__(256) void k_prep_x(const float* __restrict__ x,
        _Float16* __restrict__ xt_hi, _Float16* __restrict__ xt_lo) {
    __shared__ float tile[64][65];
    int b = blockIdx.z, n0 = blockIdx.x * 64, c0 = blockIdx.y * 64;
    const float* xb = x + (size_t)b * CC * NN;
    #pragma unroll
    for (int i = 0; i < 16; ++i) {
        int idx = i * 256 + threadIdx.x;
        int r = idx >> 6, col = idx & 63;
        tile[r][col] = xb[(size_t)(c0 + r) * NN + n0 + col];
    }
    __syncthreads();
    #pragma unroll
    for (int i = 0; i < 16; ++i) {
        int idx = i * 256 + threadIdx.x;
        int r = idx >> 6, col = idx & 63;           // r = n-local, col = c-local
        float v = tile[col][r];
        _Float16 h = (_Float16)v;
        size_t o = ((size_t)b * NN + n0 + r) * CC + c0 + col;
        xt_hi[o] = h;
        xt_lo[o] = (_Float16)(v - (float)h);
    }
}

// ---- prep: W -> single f16 plane ([3][256][256]) ----
__global__ __launch_bounds__(256) void k_prep_w(const float* __restrict__ Wq,
        const float* __restrict__ Wk, const float* __restrict__ Wv,
        _Float16* __restrict__ w) {
    int i = blockIdx.x * 256 + threadIdx.x;         // < 3*65536
    int m = i >> 16, j = i & 65535;
    const float* W = (m == 0) ? Wq : ((m == 1) ? Wk : Wv);
    w[i] = (_Float16)W[j];
}

// ---- prep: relhT[h][c] = rel_h[c][h] etc, f16 (hi only — R16) ----
__global__ __launch_bounds__(256) void k_prep_rel(const float* __restrict__ rel_h,
        const float* __restrict__ rel_w,
        _Float16* __restrict__ relhT, _Float16* __restrict__ relwT) {
    int i = blockIdx.x * 256 + threadIdx.x;         // < 48*256
    int h = i >> 8, c = i & 255;
    relhT[i] = (_Float16)rel_h[c * HH + h];
    relwT[i] = (_Float16)rel_w[c * HH + h];
}

// ---- projection GEMM, LDS-staged A (R15) + f16 passes (R16) ----
// grid (72, 16, 3); block = 32 n-rows x 256 o-cols, 4 waves (o-slice each).
// pj=0 -> qT f16 hi/lo (2-pass), pj=1 -> kT f16 (2-pass), pj=2 -> v bf16 (1-pass)
__global__ __launch_bounds__(256) void k_proj(
        const _Float16* __restrict__ xt_hi, const _Float16* __restrict__ xt_lo,
        const _Float16* __restrict__ w,
        const float* __restrict__ bq, const float* __restrict__ bk, const float* __restrict__ bv,
        _Float16* __restrict__ qt_hi, _Float16* __restrict__ qt_lo,
        _Float16* __restrict__ kt,
        __hip_bfloat16* __restrict__ vbuf) {
    __shared__ __align__(16) _Float16 lds_a[2][32][256];   // [hi/lo][row][c] 32KB
    int b = blockIdx.y, pj = blockIdx.z;
    int n0 = blockIdx.x * 32;
    int wave = threadIdx.x >> 6, lane = threadIdx.x & 63;
    int lr = lane & 15, lg = lane >> 4;
    int o0 = wave * 64;
    const size_t bN = (size_t)b * NN;
    const _Float16* wp = w + (size_t)pj * 65536;

    // stage A (XOR pre-swizzled source; both-sides): phys chunk c of row r
    // holds logical chunk c^(r&7).
    {
        int r_in = lane >> 5, chunk = lane & 31;
        #pragma unroll
        for (int j = 0; j < 4; ++j) {
            int lrow = wave * 8 + 2 * j;
            int row = lrow + r_in;
            gload_lds16(xt_hi + (bN + n0 + row) * CC + ((chunk ^ (row & 7)) * 8),
                        &lds_a[0][lrow][0]);
            gload_lds16(xt_lo + (bN + n0 + row) * CC + ((chunk ^ (row & 7)) * 8),
                        &lds_a[1][lrow][0]);
        }
    }
    __syncthreads();

    f32x4 acc[2][4] = {};
    #pragma unroll
    for (int ks = 0; ks < 8; ++ks) {
        int kk = ks * 32 + lg * 8;
        f16x8 ah[2], al[2];
        #pragma unroll
        for (int nt = 0; nt < 2; ++nt) {
            int row = nt * 16 + lr;
            int ch = ((ks * 4 + lg) ^ (lr & 7)) * 8;             // swizzled read
            ah[nt] = *reinterpret_cast<const f16x8*>(&lds_a[0][row][ch]);
            al[nt] = *reinterpret_cast<const f16x8*>(&lds_a[1][row][ch]);
        }
        #pragma unroll
        for (int ot = 0; ot < 4; ++ot) {
            int rowB = o0 + ot * 16 + lr;
            f16x8 bh = ldh8(wp + rowB * CC + kk);
            #pragma unroll
            for (int nt = 0; nt < 2; ++nt) {
                acc[nt][ot] = MFMAH(ah[nt], bh, acc[nt][ot]);
                if (pj < 2) acc[nt][ot] = MFMAH(al[nt], bh, acc[nt][ot]);
            }
        }
    }
    const float* bias = (pj == 0) ? bq : ((pj == 1) ? bk : bv);
    #pragma unroll
    for (int ot = 0; ot < 4; ++ot) {
        int o = o0 + ot * 16 + lr;
        float bb = bias[o];
        #pragma unroll
        for (int nt = 0; nt < 2; ++nt) {
            #pragma unroll
            for (int r = 0; r < 4; ++r) {
                int n = n0 + nt * 16 + lg * 4 + r;
                float y = acc[nt][ot][r] + bb;
                if (pj == 0) {
                    _Float16 h = (_Float16)y;
                    size_t off = (bN + n) * CC + o;
                    qt_hi[off] = h;
                    qt_lo[off] = (_Float16)(y - (float)h);
                } else if (pj == 1) {
                    kt[(bN + n) * CC + o] = (_Float16)y;
                } else {
                    vbuf[((size_t)b * CC + o) * NN + n] = __float2bfloat16(y);
                }
            }
        }
    }
}

// ---- pos rank-split (f16 2-pass): rhq[b][h][m] = sum_c relhT[h][c] q[b][c][m]
__global__ __launch_bounds__(256) void k_posq(
        const _Float16* __restrict__ qt_hi, const _Float16* __restrict__ qt_lo,
        const _Float16* __restrict__ relhT, const _Float16* __restrict__ relwT,
        float* __restrict__ rhq, float* __restrict__ rwq) {
    int b = blockIdx.y, m0 = blockIdx.x * 64;
    int wave = threadIdx.x >> 6, lane = threadIdx.x & 63;
    int lr = lane & 15, lg = lane >> 4;
    int m = m0 + wave * 16 + lr;                    // output column
    const size_t bN = (size_t)b * NN;
    f32x4 acc[6] = {};                              // 3 h-tiles rh, 3 w-tiles rw
    #pragma unroll
    for (int ks = 0; ks < 8; ++ks) {
        int kk = ks * 32 + lg * 8;
        f16x8 bhf = ldh8(qt_hi + (bN + m) * CC + kk);
        f16x8 blf = ldh8(qt_lo + (bN + m) * CC + kk);
        #pragma unroll
        for (int t = 0; t < 3; ++t) {
            int rowH = t * 16 + lr;
            f16x8 ahh = ldh8(relhT + rowH * CC + kk);
            acc[t] = MFMAH(ahh, bhf, acc[t]);
            acc[t] = MFMAH(ahh, blf, acc[t]);
            f16x8 awh = ldh8(relwT + rowH * CC + kk);
            acc[3 + t] = MFMAH(awh, bhf, acc[3 + t]);
            acc[3 + t] = MFMAH(awh, blf, acc[3 + t]);
        }
    }
    #pragma unroll
    for (int t = 0; t < 3; ++t) {
        #pragma unroll
        for (int r = 0; r < 4; ++r) {
            int h = t * 16 + lg * 4 + r;
            rhq[((size_t)b * HH + h) * NN + m] = acc[t][r];
            rwq[((size_t)b * HH + h) * NN + m] = acc[3 + t][r];
        }
    }
}

// ---- flash attention, split-KV, K-slice 128 (R16): 128 q-rows x tpb m-tiles --
// Per tile: ph0 {stage slice1->buf1 + V half0; S from buf0 (32 MFMAs); bar},
// ph1 {stage next slice0->buf0 + V half1; S from buf1; bar}, P+scale, bar,
// PV, bar. 4 barriers/tile. Fixed buffer roles; scale aliases dead buf1.
__global__ __launch_bounds__(512, 2) void k_attn(
        const _Float16* __restrict__ qt_hi, const _Float16* __restrict__ qt_lo,
        const _Float16* __restrict__ kt,
        const float* __restrict__ rhq, const float* __restrict__ rwq,
        const __hip_bfloat16* __restrict__ vbuf,
        __hip_bfloat16* __restrict__ o0, __hip_bfloat16* __restrict__ o1,
        __hip_bfloat16* __restrict__ o2, __hip_bfloat16* __restrict__ o3,
        float2* __restrict__ ml, int tpb) {
    __shared__ __align__(16) _Float16 lds_k[2][64][128];          // [slice][row][k] 32KB
    __shared__ __align__(16) __hip_bfloat16 lds_v[256][64];       // [c][m] 32KB (swizzled)
    __shared__ __align__(16) __hip_bfloat16 lds_p[128][64];       // shared P tile 16KB (swizzled)
    float* lds_scale = reinterpret_cast<float*>(&lds_k[1][0][0]); // dead after ph1-end bar
    int b = blockIdx.y;
    int n0 = blockIdx.x * 128;
    int z = blockIdx.z;
    int t0 = z * tpb, t_end = t0 + tpb;
    __hip_bfloat16* opart = (z == 0) ? o0 : (z == 1) ? o1 : (z == 2) ? o2 : o3;
    int wave = threadIdx.x >> 6, lane = threadIdx.x & 63;
    int lr = lane & 15, lg = lane >> 4;
    int rowA = n0 + wave * 16 + lr;
    const size_t bN = (size_t)b * NN;

    f16x8 qh[8], ql[8];
    #pragma unroll
    for (int ks = 0; ks < 8; ++ks) {
        int kk = ks * 32 + lg * 8;
        qh[ks] = ldh8(qt_hi + (bN + rowA) * CC + kk);
        ql[ks] = ldh8(qt_lo + (bN + rowA) * CC + kk);
    }
    int hn[4], wn[4];
    #pragma unroll
    for (int r = 0; r < 4; ++r) {
        int n = n0 + wave * 16 + lg * 4 + r;
        hn[r] = n % HH;
        wn[r] = n / HH;
    }
    const float* rhq_b = rhq + (size_t)b * HH * NN;
    const float* rwq_b = rwq + (size_t)b * HH * NN;

    int nh = wave >> 2;                 // n-half
    int cq = wave & 3;                  // c-quarter
    f32x4 oacc[4][4] = {};              // [nf][cf]
    float mrun[4] = {-1e30f, -1e30f, -1e30f, -1e30f};
    float lrun[4] = {0.f, 0.f, 0.f, 0.f};

    // K staging ([64][128] f16, 256B rows, 16 chunks): per call 4 rows.
    int krin = lane >> 4, kch = lane & 15;
    auto STAGE_K = [&](int buf, int m0s, int k0) {
        #pragma unroll
        for (int j = 0; j < 2; ++j) {
            int lrow = wave * 8 + j * 4;
            int grow = lrow + krin;
            gload_lds16(kt + (bN + m0s + grow) * CC + k0 + ((kch ^ (grow & 7)) * 8),
                        &lds_k[buf][lrow][0]);
        }
    };
    // V staging ([256][64] bf16, 128B rows, 8 chunks): half (128 c-rows) per phase.
    int srl = lane >> 3;
    int sch = ((lane & 7) ^ srl) * 8;
    auto STAGE_V = [&](int half, int m0s) {
        #pragma unroll
        for (int j = 0; j < 2; ++j) {
            int lrow = half * 128 + wave * 16 + j * 8;
            int crow = lrow + srl;
            gload_lds16(vbuf + ((size_t)b * CC + crow) * NN + m0s + sch, &lds_v[lrow][0]);
        }
    };

    STAGE_K(0, t0 * 64, 0);
    __syncthreads();

    for (int t = t0; t < t_end; ++t) {
        int m0 = t * 64;
        float padd[4][4];
        #pragma unroll
        for (int mt = 0; mt < 4; ++mt) {
            int m = m0 + mt * 16 + lr;
            #pragma unroll
            for (int r = 0; r < 4; ++r)
                padd[mt][r] = rhq_b[(size_t)hn[r] * NN + m] + rwq_b[(size_t)wn[r] * NN + m];
        }
        f32x4 sacc[4] = {};
        #pragma unroll
        for (int s = 0; s < 2; ++s) {
            if (s == 0) {
                STAGE_K(1, m0, 128);                  // slice1 of current tile
                STAGE_V(0, m0);
            } else {
                int mn = (t + 1 < t_end) ? (t + 1) * 64 : t0 * 64;
                STAGE_K(0, mn, 0);                    // next tile slice0
                STAGE_V(1, m0);
            }
            #pragma unroll
            for (int ks = 0; ks < 4; ++ks) {
                #pragma unroll
                for (int mt = 0; mt < 4; ++mt) {
                    int row = mt * 16 + lr;
                    int ch = ((ks * 4 + lg) ^ (lr & 7)) * 8;      // swizzled read
                    f16x8 bh = *reinterpret_cast<const f16x8*>(&lds_k[s][row][ch]);
                    sacc[mt] = MFMAH(qh[s * 4 + ks], bh, sacc[mt]);
                    sacc[mt] = MFMAH(ql[s * 4 + ks], bh, sacc[mt]);
                }
            }
            __syncthreads();
        }
        #pragma unroll
        for (int mt = 0; mt < 4; ++mt)
            #pragma unroll
            for (int r = 0; r < 4; ++r)
                sacc[mt][r] += padd[mt][r];
        float scl_r[4];
        #pragma unroll
        for (int r = 0; r < 4; ++r) {
            float smax = fmaxf(fmaxf(sacc[0][r], sacc[1][r]), fmaxf(sacc[2][r], sacc[3][r]));
            #pragma unroll
            for (int mk = 1; mk <= 8; mk <<= 1)
                smax = fmaxf(smax, __shfl_xor(smax, mk));
            float mnew = fmaxf(mrun[r], smax);
            scl_r[r] = __expf(mrun[r] - mnew);
            float rsum = 0.f;
            #pragma unroll
            for (int mt = 0; mt < 4; ++mt) {
                float p = __expf(sacc[mt][r] - mnew);
                sacc[mt][r] = p;
                rsum += p;
            }
            #pragma unroll
            for (int mk = 1; mk <= 8; mk <<= 1)
                rsum += __shfl_xor(rsum, mk);
            lrun[r] = lrun[r] * scl_r[r] + rsum;
            mrun[r] = mnew;
        }
        // P + scale -> LDS (scale into buf1: dead after ph1-end barrier,
        // restaged only at next tile's ph0 which follows the PV-end barrier)
        #pragma unroll
        for (int mt = 0; mt < 4; ++mt) {
            #pragma unroll
            for (int r = 0; r < 4; ++r) {
                int prow = wave * 16 + lg * 4 + r;
                int pcol = mt * 16 + lr;
                int pcol_s = (((pcol >> 3) ^ (prow & 7)) << 3) | (pcol & 7);
                lds_p[prow][pcol_s] = __float2bfloat16(sacc[mt][r]);
            }
        }
        if (lr == 0) {
            #pragma unroll
            for (int r = 0; r < 4; ++r)
                lds_scale[wave * 16 + lg * 4 + r] = scl_r[r];
        }
        __syncthreads();
        f32x4 scl4[4];
        #pragma unroll
        for (int nf = 0; nf < 4; ++nf) {
            scl4[nf] = *reinterpret_cast<const f32x4*>(&lds_scale[nh * 64 + nf * 16 + lg * 4]);
            #pragma unroll
            for (int cf = 0; cf < 4; ++cf)
                oacc[nf][cf] *= scl4[nf];
        }
        #pragma unroll
        for (int ks2 = 0; ks2 < 2; ++ks2) {
            bf16x8 pa[4];
            #pragma unroll
            for (int nf = 0; nf < 4; ++nf) {
                int prow = nh * 64 + nf * 16 + lr;
                int pch = ((ks2 * 4 + lg) ^ (lr & 7)) * 8;
                pa[nf] = *reinterpret_cast<const bf16x8*>(&lds_p[prow][pch]);
            }
            #pragma unroll
            for (int cf = 0; cf < 4; ++cf) {
                int vrow = cq * 64 + cf * 16 + lr;
                int vch = ((ks2 * 4 + lg) ^ (lr & 7)) * 8;
                bf16x8 bv = *reinterpret_cast<const bf16x8*>(&lds_v[vrow][vch]);
                #pragma unroll
                for (int nf = 0; nf < 4; ++nf)
                    oacc[nf][cf] = MFMA(pa[nf], bv, oacc[nf][cf]);
            }
        }
        __syncthreads();
    }
    if (lr == 0) {
        #pragma unroll
        for (int r = 0; r < 4; ++r) {
            int n = n0 + wave * 16 + lg * 4 + r;
            ml[((size_t)z * BB + b) * NN + n] = make_float2(mrun[r], lrun[r]);
        }
    }
    #pragma unroll
    for (int nf = 0; nf < 4; ++nf) {
        int nbase = n0 + nh * 64 + nf * 16 + lg * 4;
        #pragma unroll
        for (int cf = 0; cf < 4; ++cf) {
            int c = cq * 64 + cf * 16 + lr;
            union { ushort4 u4; unsigned short us[4]; } pk;
            #pragma unroll
            for (int j = 0; j < 4; ++j) {
                __hip_bfloat16 hv = __float2bfloat16(oacc[nf][cf][j]);
                pk.us[j] = *reinterpret_cast<unsigned short*>(&hv);
            }
            *reinterpret_cast<ushort4*>(&opart[((size_t)b * CC + c) * NN + nbase]) = pk.u4;
        }
    }
}

// ---- combine: out[b][c][n] = sum_z o_z*exp(m_z-M) / sum_z l_z*exp(m_z-M) ----
__global__ __launch_bounds__(256) void k_combine(
        const __hip_bfloat16* __restrict__ o0, const __hip_bfloat16* __restrict__ o1,
        const __hip_bfloat16* __restrict__ o2, const __hip_bfloat16* __restrict__ o3,
        const float2* __restrict__ ml, int nsplit, float* __restrict__ out) {
    size_t idx = ((size_t)blockIdx.x * 256 + threadIdx.x) * 4;   // over B*CC*NN
    int n4 = (int)(idx % NN);
    int c  = (int)((idx / NN) % CC);
    int b  = (int)(idx / ((size_t)NN * CC));
    float M[4] = {-1e30f, -1e30f, -1e30f, -1e30f};
    for (int zz = 0; zz < nsplit; ++zz) {
        #pragma unroll
        for (int j = 0; j < 4; ++j)
            M[j] = fmaxf(M[j], ml[((size_t)zz * BB + b) * NN + n4 + j].x);
    }
    float num[4] = {}, den[4] = {};
    for (int zz = 0; zz < nsplit; ++zz) {
        const __hip_bfloat16* op = (zz == 0) ? o0 : (zz == 1) ? o1 : (zz == 2) ? o2 : o3;
        ushort4 u = *reinterpret_cast<const ushort4*>(op + ((size_t)b * CC + c) * NN + n4);
        unsigned short us[4] = {u.x, u.y, u.z, u.w};
        #pragma unroll
        for (int j = 0; j < 4; ++j) {
            float2 v = ml[((size_t)zz * BB + b) * NN + n4 + j];
            float w = __expf(v.x - M[j]);
            num[j] += bf2f(us[j]) * w;
            den[j] += v.y * w;
        }
    }
    f32x4 o;
    #pragma unroll
    for (int j = 0; j < 4; ++j) o[j] = num[j] / den[j];
    *reinterpret_cast<f32x4*>(&out[idx]) = o;
}

extern "C" void kernel_launch(void* const* d_in, const int* in_sizes, int n_in,
                              void* d_out, int out_size, void* d_ws, size_t ws_size,
                              hipStream_t stream) {
    const float* x     = (const float*)d_in[0];
    const float* Wq    = (const float*)d_in[1];
    const float* bq    = (const float*)d_in[2];
    const float* Wk    = (const float*)d_in[3];
    const float* bk    = (const float*)d_in[4];
    const float* Wv    = (const float*)d_in[5];
    const float* bv    = (const float*)d_in[6];
    const float* rel_h = (const float*)d_in[7];
    const float* rel_w = (const float*)d_in[8];
    float* out = (float*)d_out;

    size_t off = 0;
    auto carve = [&](size_t bytes) {
        void* p = (char*)d_ws + off;
        off += (bytes + 255) & ~(size_t)255;
        return p;
    };
    const size_t sz_t = (size_t)BB * NN * CC * 2;   // one 2B plane = 18.87 MB
    _Float16* xt_hi  = (_Float16*)carve(sz_t);
    _Float16* xt_lo  = (_Float16*)carve(sz_t);
    _Float16* qt_hi  = (_Float16*)carve(sz_t);
    _Float16* qt_lo  = (_Float16*)carve(sz_t);
    _Float16* kt     = (_Float16*)carve(sz_t);
    __hip_bfloat16* vbuf = (__hip_bfloat16*)carve(sz_t);
    _Float16* relhT = (_Float16*)carve((size_t)HH * CC * 2);
    _Float16* relwT = (_Float16*)carve((size_t)HH * CC * 2);
    _Float16* w     = (_Float16*)carve((size_t)3 * CC * CC * 2);
    float* rhq = (float*)carve((size_t)BB * HH * NN * 4);
    float* rwq = (float*)carve((size_t)BB * HH * NN * 4);
    float2* ml = (float2*)carve((size_t)4 * BB * NN * sizeof(float2));
    if (off > ws_size) return;   // base workspace too small -> visible failure

    // split-KV partial planes: 0/1 alias dead xt_hi/xt_lo; 2/3 only if ws fits
    __hip_bfloat16* o0 = (__hip_bfloat16*)xt_hi;
    __hip_bfloat16* o1 = (__hip_bfloat16*)xt_lo;
    __hip_bfloat16* o2 = nullptr;
    __hip_bfloat16* o3 = nullptr;
    int nsplit = 2;
    {
        size_t save = off;
        __hip_bfloat16* p2 = (__hip_bfloat16*)carve(sz_t);
        __hip_bfloat16* p3 = (__hip_bfloat16*)carve(sz_t);
        if (off <= ws_size) { nsplit = 4; o2 = p2; o3 = p3; }
        else { off = save; }
    }
    int tpb = 36 / nsplit;

    k_prep_x<<<dim3(NN / 64, CC / 64, BB), 256, 0, stream>>>(x, xt_hi, xt_lo);
    k_prep_w<<<dim3(3 * CC * CC / 256), 256, 0, stream>>>(Wq, Wk, Wv, w);
    k_prep_rel<<<dim3(HH * CC / 256), 256, 0, stream>>>(rel_h, rel_w, relhT, relwT);
    k_proj<<<dim3(NN / 32, BB, 3), 256, 0, stream>>>(
        xt_hi, xt_lo, w, bq, bk, bv, qt_hi, qt_lo, kt, vbuf);
    k_posq<<<dim3(NN / 64, BB), 256, 0, stream>>>(
        qt_hi, qt_lo, relhT, relwT, rhq, rwq);
    k_attn<<<dim3(NN / 128, BB, nsplit), 512, 0, stream>>>(
        qt_hi, qt_lo, kt, rhq, rwq, vbuf, o0, o1, o2, o3, ml, tpb);
    k_combine<<<dim3((size_t)BB * CC * NN / 1024), 256, 0, stream>>>(
        o0, o1, o2, o3, ml, nsplit, out);
}

// Round 17
// 459.056 us; speedup vs baseline: 1.5793x; 1.1515x over previous
//
#include <hip/hip_runtime.h>
#include <hip/hip_bf16.h>

// MHSA: B=16, C=256, H=W=48, N=2304.
// S[b,n,m] = q[b,:,n]·k[b,:,m] + rhq[b][n%48][m] + rwq[b][n/48][m]
// att = softmax_m(S); out[b,c,n] = sum_m v[b,c,m] att[n,m]
// Numerics (R17): attn S uses q SINGLE f16 (1-pass) — q-quant logit err
// 0.0046 rms adds in quadrature (0.0075->0.0088); posq keeps 2-plane q.
// Defer-max (T13, THR=8): skip oacc rescale when no wave's max grew — exact.
// Attn: split-KV (R13) + K-slice 128 (R16). Side kernels = R16.

#define BB 16
#define CC 256
#define HH 48
#define NN 2304

typedef float f32x4 __attribute__((ext_vector_type(4)));
typedef short bf16x8 __attribute__((ext_vector_type(8)));
typedef _Float16 f16x8 __attribute__((ext_vector_type(8)));

#define MFMA(a, b, c)  __builtin_amdgcn_mfma_f32_16x16x32_bf16((a), (b), (c), 0, 0, 0)
#define MFMAH(a, b, c) __builtin_amdgcn_mfma_f32_16x16x32_f16((a), (b), (c), 0, 0, 0)

__device__ inline bf16x8 ldg8(const __hip_bfloat16* p) {
    return *reinterpret_cast<const bf16x8*>(p);
}
__device__ inline f16x8 ldh8(const _Float16* p) {
    return *reinterpret_cast<const f16x8*>(p);
}
__device__ inline float bf2f(unsigned short v) {
    unsigned u = (unsigned)v << 16;
    float f;
    __builtin_memcpy(&f, &u, 4);
    return f;
}

typedef __attribute__((address_space(3))) unsigned int lds_uint;
typedef const __attribute__((address_space(1))) unsigned int gbl_uint;

__device__ inline void gload_lds16(const void* g, void* l) {
    __builtin_amdgcn_global_load_lds((gbl_uint*)g, (lds_uint*)l, 16, 0, 0);
}

// ---- prep: transpose x [b][c][n] -> xT [b][n][c], split into f16 hi/lo ----
__global__ __launch_bounds__(256) void k_prep_x(const float* __restrict__ x,
        _Float16* __restrict__ xt_hi, _Float16* __restrict__ xt_lo) {
    __shared__ float tile[64][65];
    int b = blockIdx.z, n0 = blockIdx.x * 64, c0 = blockIdx.y * 64;
    const float* xb = x + (size_t)b * CC * NN;
    #pragma unroll
    for (int i = 0; i < 16; ++i) {
        int idx = i * 256 + threadIdx.x;
        int r = idx >> 6, col = idx & 63;
        tile[r][col] = xb[(size_t)(c0 + r) * NN + n0 + col];
    }
    __syncthreads();
    #pragma unroll
    for (int i = 0; i < 16; ++i) {
        int idx = i * 256 + threadIdx.x;
        int r = idx >> 6, col = idx & 63;           // r = n-local, col = c-local
        float v = tile[col][r];
        _Float16 h = (_Float16)v;
        size_t o = ((size_t)b * NN + n0 + r) * CC + c0 + col;
        xt_hi[o] = h;
        xt_lo[o] = (_Float16)(v - (float)h);
    }
}

// ---- prep: W -> single f16 plane ([3][256][256]) ----
__global__ __launch_bounds__(256) void k_prep_w(const float* __restrict__ Wq,
        const float* __restrict__ Wk, const float* __restrict__ Wv,
        _Float16* __restrict__ w) {
    int i = blockIdx.x * 256 + threadIdx.x;         // < 3*65536
    int m = i >> 16, j = i & 65535;
    const float* W = (m == 0) ? Wq : ((m == 1) ? Wk : Wv);
    w[i] = (_Float16)W[j];
}

// ---- prep: relhT[h][c] = rel_h[c][h] etc, f16 ----
__global__ __launch_bounds__(256) void k_prep_rel(const float* __restrict__ rel_h,
        const float* __restrict__ rel_w,
        _Float16* __restrict__ relhT, _Float16* __restrict__ relwT) {
    int i = blockIdx.x * 256 + threadIdx.x;         // < 48*256
    int h = i >> 8, c = i & 255;
    relhT[i] = (_Float16)rel_h[c * HH + h];
    relwT[i] = (_Float16)rel_w[c * HH + h];
}

// ---- projection GEMM, LDS-staged A (R15) + f16 passes (R16) ----
// grid (72, 16, 3); block = 32 n-rows x 256 o-cols, 4 waves (o-slice each).
// pj=0 -> qT f16 hi/lo (2-pass), pj=1 -> kT f16 (2-pass), pj=2 -> v bf16 (1-pass)
__global__ __launch_bounds__(256) void k_proj(
        const _Float16* __restrict__ xt_hi, const _Float16* __restrict__ xt_lo,
        const _Float16* __restrict__ w,
        const float* __restrict__ bq, const float* __restrict__ bk, const float* __restrict__ bv,
        _Float16* __restrict__ qt_hi, _Float16* __restrict__ qt_lo,
        _Float16* __restrict__ kt,
        __hip_bfloat16* __restrict__ vbuf) {
    __shared__ __align__(16) _Float16 lds_a[2][32][256];   // [hi/lo][row][c] 32KB
    int b = blockIdx.y, pj = blockIdx.z;
    int n0 = blockIdx.x * 32;
    int wave = threadIdx.x >> 6, lane = threadIdx.x & 63;
    int lr = lane & 15, lg = lane >> 4;
    int o0 = wave * 64;
    const size_t bN = (size_t)b * NN;
    const _Float16* wp = w + (size_t)pj * 65536;

    {
        int r_in = lane >> 5, chunk = lane & 31;
        #pragma unroll
        for (int j = 0; j < 4; ++j) {
            int lrow = wave * 8 + 2 * j;
            int row = lrow + r_in;
            gload_lds16(xt_hi + (bN + n0 + row) * CC + ((chunk ^ (row & 7)) * 8),
                        &lds_a[0][lrow][0]);
            gload_lds16(xt_lo + (bN + n0 + row) * CC + ((chunk ^ (row & 7)) * 8),
                        &lds_a[1][lrow][0]);
        }
    }
    __syncthreads();

    f32x4 acc[2][4] = {};
    #pragma unroll
    for (int ks = 0; ks < 8; ++ks) {
        int kk = ks * 32 + lg * 8;
        f16x8 ah[2], al[2];
        #pragma unroll
        for (int nt = 0; nt < 2; ++nt) {
            int row = nt * 16 + lr;
            int ch = ((ks * 4 + lg) ^ (lr & 7)) * 8;             // swizzled read
            ah[nt] = *reinterpret_cast<const f16x8*>(&lds_a[0][row][ch]);
            al[nt] = *reinterpret_cast<const f16x8*>(&lds_a[1][row][ch]);
        }
        #pragma unroll
        for (int ot = 0; ot < 4; ++ot) {
            int rowB = o0 + ot * 16 + lr;
            f16x8 bh = ldh8(wp + rowB * CC + kk);
            #pragma unroll
            for (int nt = 0; nt < 2; ++nt) {
                acc[nt][ot] = MFMAH(ah[nt], bh, acc[nt][ot]);
                if (pj < 2) acc[nt][ot] = MFMAH(al[nt], bh, acc[nt][ot]);
            }
        }
    }
    const float* bias = (pj == 0) ? bq : ((pj == 1) ? bk : bv);
    #pragma unroll
    for (int ot = 0; ot < 4; ++ot) {
        int o = o0 + ot * 16 + lr;
        float bb = bias[o];
        #pragma unroll
        for (int nt = 0; nt < 2; ++nt) {
            #pragma unroll
            for (int r = 0; r < 4; ++r) {
                int n = n0 + nt * 16 + lg * 4 + r;
                float y = acc[nt][ot][r] + bb;
                if (pj == 0) {
                    _Float16 h = (_Float16)y;
                    size_t off = (bN + n) * CC + o;
                    qt_hi[off] = h;
                    qt_lo[off] = (_Float16)(y - (float)h);
                } else if (pj == 1) {
                    kt[(bN + n) * CC + o] = (_Float16)y;
                } else {
                    vbuf[((size_t)b * CC + o) * NN + n] = __float2bfloat16(y);
                }
            }
        }
    }
}

// ---- pos rank-split (f16 2-pass, 2-plane q): rhq = relhT q, rwq = relwT q ---
__global__ __launch_bounds__(256) void k_posq(
        const _Float16* __restrict__ qt_hi, const _Float16* __restrict__ qt_lo,
        const _Float16* __restrict__ relhT, const _Float16* __restrict__ relwT,
        float* __restrict__ rhq, float* __restrict__ rwq) {
    int b = blockIdx.y, m0 = blockIdx.x * 64;
    int wave = threadIdx.x >> 6, lane = threadIdx.x & 63;
    int lr = lane & 15, lg = lane >> 4;
    int m = m0 + wave * 16 + lr;                    // output column
    const size_t bN = (size_t)b * NN;
    f32x4 acc[6] = {};                              // 3 h-tiles rh, 3 w-tiles rw
    #pragma unroll
    for (int ks = 0; ks < 8; ++ks) {
        int kk = ks * 32 + lg * 8;
        f16x8 bhf = ldh8(qt_hi + (bN + m) * CC + kk);
        f16x8 blf = ldh8(qt_lo + (bN + m) * CC + kk);
        #pragma unroll
        for (int t = 0; t < 3; ++t) {
            int rowH = t * 16 + lr;
            f16x8 ahh = ldh8(relhT + rowH * CC + kk);
            acc[t] = MFMAH(ahh, bhf, acc[t]);
            acc[t] = MFMAH(ahh, blf, acc[t]);
            f16x8 awh = ldh8(relwT + rowH * CC + kk);
            acc[3 + t] = MFMAH(awh, bhf, acc[3 + t]);
            acc[3 + t] = MFMAH(awh, blf, acc[3 + t]);
        }
    }
    #pragma unroll
    for (int t = 0; t < 3; ++t) {
        #pragma unroll
        for (int r = 0; r < 4; ++r) {
            int h = t * 16 + lg * 4 + r;
            rhq[((size_t)b * HH + h) * NN + m] = acc[t][r];
            rwq[((size_t)b * HH + h) * NN + m] = acc[3 + t][r];
        }
    }
}

// ---- flash attention, split-KV, K-slice 128, q 1-pass, defer-max (R17) ----
// Per tile: ph0 {stage K slice1 + V half0; S from slice0 (16 MFMA/wave); bar},
// ph1 {stage next K slice0 + V half1; S from slice1; bar}, softmax w/ defer-max,
// P+scale+votes, bar, PV (rescale only if any wave voted), bar.
__global__ __launch_bounds__(512, 2) void k_attn(
        const _Float16* __restrict__ qt_hi,
        const _Float16* __restrict__ kt,
        const float* __restrict__ rhq, const float* __restrict__ rwq,
        const __hip_bfloat16* __restrict__ vbuf,
        __hip_bfloat16* __restrict__ o0, __hip_bfloat16* __restrict__ o1,
        __hip_bfloat16* __restrict__ o2, __hip_bfloat16* __restrict__ o3,
        float2* __restrict__ ml, int tpb) {
    __shared__ __align__(16) _Float16 lds_k[2][64][128];          // [slice][row][k] 32KB
    __shared__ __align__(16) __hip_bfloat16 lds_v[256][64];       // [c][m] 32KB (swizzled)
    __shared__ __align__(16) __hip_bfloat16 lds_p[128][64];       // shared P tile 16KB (swizzled)
    // scale + per-wave rescale votes aliased into buf1 (staged over at ph0,
    // rewritten before every use each tile -> deterministic).
    float* lds_scale = reinterpret_cast<float*>(&lds_k[1][0][0]);
    int*   lds_flag  = reinterpret_cast<int*>(lds_scale + 128);   // [8]
    int b = blockIdx.y;
    int n0 = blockIdx.x * 128;
    int z = blockIdx.z;
    int t0 = z * tpb, t_end = t0 + tpb;
    __hip_bfloat16* opart = (z == 0) ? o0 : (z == 1) ? o1 : (z == 2) ? o2 : o3;
    int wave = threadIdx.x >> 6, lane = threadIdx.x & 63;
    int lr = lane & 15, lg = lane >> 4;
    int rowA = n0 + wave * 16 + lr;
    const size_t bN = (size_t)b * NN;

    f16x8 qh[8];
    #pragma unroll
    for (int ks = 0; ks < 8; ++ks) {
        int kk = ks * 32 + lg * 8;
        qh[ks] = ldh8(qt_hi + (bN + rowA) * CC + kk);
    }
    int hn[4], wn[4];
    #pragma unroll
    for (int r = 0; r < 4; ++r) {
        int n = n0 + wave * 16 + lg * 4 + r;
        hn[r] = n % HH;
        wn[r] = n / HH;
    }
    const float* rhq_b = rhq + (size_t)b * HH * NN;
    const float* rwq_b = rwq + (size_t)b * HH * NN;

    int nh = wave >> 2;                 // n-half
    int cq = wave & 3;                  // c-quarter
    f32x4 oacc[4][4] = {};              // [nf][cf]
    float mrun[4] = {-1e30f, -1e30f, -1e30f, -1e30f};
    float lrun[4] = {0.f, 0.f, 0.f, 0.f};

    // K staging ([64][128] f16, 256B rows, 16 chunks): per call 4 rows.
    int krin = lane >> 4, kch = lane & 15;
    auto STAGE_K = [&](int buf, int m0s, int k0) {
        #pragma unroll
        for (int j = 0; j < 2; ++j) {
            int lrow = wave * 8 + j * 4;
            int grow = lrow + krin;
            gload_lds16(kt + (bN + m0s + grow) * CC + k0 + ((kch ^ (grow & 7)) * 8),
                        &lds_k[buf][lrow][0]);
        }
    };
    // V staging ([256][64] bf16, 128B rows, 8 chunks): half (128 c-rows) per phase.
    int srl = lane >> 3;
    int sch = ((lane & 7) ^ srl) * 8;
    auto STAGE_V = [&](int half, int m0s) {
        #pragma unroll
        for (int j = 0; j < 2; ++j) {
            int lrow = half * 128 + wave * 16 + j * 8;
            int crow = lrow + srl;
            gload_lds16(vbuf + ((size_t)b * CC + crow) * NN + m0s + sch, &lds_v[lrow][0]);
        }
    };

    STAGE_K(0, t0 * 64, 0);
    __syncthreads();

    for (int t = t0; t < t_end; ++t) {
        int m0 = t * 64;
        float padd[4][4];
        #pragma unroll
        for (int mt = 0; mt < 4; ++mt) {
            int m = m0 + mt * 16 + lr;
            #pragma unroll
            for (int r = 0; r < 4; ++r)
                padd[mt][r] = rhq_b[(size_t)hn[r] * NN + m] + rwq_b[(size_t)wn[r] * NN + m];
        }
        f32x4 sacc[4] = {};
        #pragma unroll
        for (int s = 0; s < 2; ++s) {
            if (s == 0) {
                STAGE_K(1, m0, 128);                  // slice1 of current tile
                STAGE_V(0, m0);
            } else {
                int mn = (t + 1 < t_end) ? (t + 1) * 64 : t0 * 64;
                STAGE_K(0, mn, 0);                    // next tile slice0
                STAGE_V(1, m0);
            }
            #pragma unroll
            for (int ks = 0; ks < 4; ++ks) {
                #pragma unroll
                for (int mt = 0; mt < 4; ++mt) {
                    int row = mt * 16 + lr;
                    int ch = ((ks * 4 + lg) ^ (lr & 7)) * 8;      // swizzled read
                    f16x8 bh = *reinterpret_cast<const f16x8*>(&lds_k[s][row][ch]);
                    sacc[mt] = MFMAH(qh[s * 4 + ks], bh, sacc[mt]);
                }
            }
            __syncthreads();
        }
        #pragma unroll
        for (int mt = 0; mt < 4; ++mt)
            #pragma unroll
            for (int r = 0; r < 4; ++r)
                sacc[mt][r] += padd[mt][r];
        // ---- online softmax with defer-max (THR=8): exact algebra ----
        float scl_r[4];
        bool lane_need = false;
        #pragma unroll
        for (int r = 0; r < 4; ++r) {
            float smax = fmaxf(fmaxf(sacc[0][r], sacc[1][r]), fmaxf(sacc[2][r], sacc[3][r]));
            #pragma unroll
            for (int mk = 1; mk <= 8; mk <<= 1)
                smax = fmaxf(smax, __shfl_xor(smax, mk));
            bool need = smax > mrun[r] + 8.0f;
            lane_need |= need;
            if (need) {
                scl_r[r] = __expf(mrun[r] - smax);    // exp(-1e30)=0 on first tile
                mrun[r] = smax;
            } else {
                scl_r[r] = 1.0f;
            }
            float rsum = 0.f;
            #pragma unroll
            for (int mt = 0; mt < 4; ++mt) {
                float p = __expf(sacc[mt][r] - mrun[r]);   // bounded by e^8
                sacc[mt][r] = p;
                rsum += p;
            }
            #pragma unroll
            for (int mk = 1; mk <= 8; mk <<= 1)
                rsum += __shfl_xor(rsum, mk);
            lrun[r] = lrun[r] * scl_r[r] + rsum;
        }
        bool wave_need = __any(lane_need);
        // ---- P + scale + vote -> LDS ----
        #pragma unroll
        for (int mt = 0; mt < 4; ++mt) {
            #pragma unroll
            for (int r = 0; r < 4; ++r) {
                int prow = wave * 16 + lg * 4 + r;
                int pcol = mt * 16 + lr;
                int pcol_s = (((pcol >> 3) ^ (prow & 7)) << 3) | (pcol & 7);
                lds_p[prow][pcol_s] = __float2bfloat16(sacc[mt][r]);
            }
        }
        if (lr == 0) {
            #pragma unroll
            for (int r = 0; r < 4; ++r)
                lds_scale[wave * 16 + lg * 4 + r] = scl_r[r];
        }
        if (lane == 0) lds_flag[wave] = wave_need ? 1 : 0;   // unconditional write
        __syncthreads();
        // ---- PV: rescale only if any wave voted (common case: skip) ----
        int4 f0 = *reinterpret_cast<const int4*>(&lds_flag[0]);
        int4 f1 = *reinterpret_cast<const int4*>(&lds_flag[4]);
        bool do_scale = (f0.x | f0.y | f0.z | f0.w | f1.x | f1.y | f1.z | f1.w) != 0;
        if (do_scale) {
            #pragma unroll
            for (int nf = 0; nf < 4; ++nf) {
                f32x4 s4 = *reinterpret_cast<const f32x4*>(&lds_scale[nh * 64 + nf * 16 + lg * 4]);
                #pragma unroll
                for (int cf = 0; cf < 4; ++cf)
                    oacc[nf][cf] *= s4;
            }
        }
        #pragma unroll
        for (int ks2 = 0; ks2 < 2; ++ks2) {
            bf16x8 pa[4];
            #pragma unroll
            for (int nf = 0; nf < 4; ++nf) {
                int prow = nh * 64 + nf * 16 + lr;
                int pch = ((ks2 * 4 + lg) ^ (lr & 7)) * 8;
                pa[nf] = *reinterpret_cast<const bf16x8*>(&lds_p[prow][pch]);
            }
            #pragma unroll
            for (int cf = 0; cf < 4; ++cf) {
                int vrow = cq * 64 + cf * 16 + lr;
                int vch = ((ks2 * 4 + lg) ^ (lr & 7)) * 8;
                bf16x8 bv = *reinterpret_cast<const bf16x8*>(&lds_v[vrow][vch]);
                #pragma unroll
                for (int nf = 0; nf < 4; ++nf)
                    oacc[nf][cf] = MFMA(pa[nf], bv, oacc[nf][cf]);
            }
        }
        __syncthreads();
    }
    if (lr == 0) {
        #pragma unroll
        for (int r = 0; r < 4; ++r) {
            int n = n0 + wave * 16 + lg * 4 + r;
            ml[((size_t)z * BB + b) * NN + n] = make_float2(mrun[r], lrun[r]);
        }
    }
    #pragma unroll
    for (int nf = 0; nf < 4; ++nf) {
        int nbase = n0 + nh * 64 + nf * 16 + lg * 4;
        #pragma unroll
        for (int cf = 0; cf < 4; ++cf) {
            int c = cq * 64 + cf * 16 + lr;
            union { ushort4 u4; unsigned short us[4]; } pk;
            #pragma unroll
            for (int j = 0; j < 4; ++j) {
                __hip_bfloat16 hv = __float2bfloat16(oacc[nf][cf][j]);
                pk.us[j] = *reinterpret_cast<unsigned short*>(&hv);
            }
            *reinterpret_cast<ushort4*>(&opart[((size_t)b * CC + c) * NN + nbase]) = pk.u4;
        }
    }
}

// ---- combine: out[b][c][n] = sum_z o_z*exp(m_z-M) / sum_z l_z*exp(m_z-M) ----
__global__ __launch_bounds__(256) void k_combine(
        const __hip_bfloat16* __restrict__ o0, const __hip_bfloat16* __restrict__ o1,
        const __hip_bfloat16* __restrict__ o2, const __hip_bfloat16* __restrict__ o3,
        const float2* __restrict__ ml, int nsplit, float* __restrict__ out) {
    size_t idx = ((size_t)blockIdx.x * 256 + threadIdx.x) * 4;   // over B*CC*NN
    int n4 = (int)(idx % NN);
    int c  = (int)((idx / NN) % CC);
    int b  = (int)(idx / ((size_t)NN * CC));
    float M[4] = {-1e30f, -1e30f, -1e30f, -1e30f};
    for (int zz = 0; zz < nsplit; ++zz) {
        #pragma unroll
        for (int j = 0; j < 4; ++j)
            M[j] = fmaxf(M[j], ml[((size_t)zz * BB + b) * NN + n4 + j].x);
    }
    float num[4] = {}, den[4] = {};
    for (int zz = 0; zz < nsplit; ++zz) {
        const __hip_bfloat16* op = (zz == 0) ? o0 : (zz == 1) ? o1 : (zz == 2) ? o2 : o3;
        ushort4 u = *reinterpret_cast<const ushort4*>(op + ((size_t)b * CC + c) * NN + n4);
        unsigned short us[4] = {u.x, u.y, u.z, u.w};
        #pragma unroll
        for (int j = 0; j < 4; ++j) {
            float2 v = ml[((size_t)zz * BB + b) * NN + n4 + j];
            float w = __expf(v.x - M[j]);
            num[j] += bf2f(us[j]) * w;
            den[j] += v.y * w;
        }
    }
    f32x4 o;
    #pragma unroll
    for (int j = 0; j < 4; ++j) o[j] = num[j] / den[j];
    *reinterpret_cast<f32x4*>(&out[idx]) = o;
}

extern "C" void kernel_launch(void* const* d_in, const int* in_sizes, int n_in,
                              void* d_out, int out_size, void* d_ws, size_t ws_size,
                              hipStream_t stream) {
    const float* x     = (const float*)d_in[0];
    const float* Wq    = (const float*)d_in[1];
    const float* bq    = (const float*)d_in[2];
    const float* Wk    = (const float*)d_in[3];
    const float* bk    = (const float*)d_in[4];
    const float* Wv    = (const float*)d_in[5];
    const float* bv    = (const float*)d_in[6];
    const float* rel_h = (const float*)d_in[7];
    const float* rel_w = (const float*)d_in[8];
    float* out = (float*)d_out;

    size_t off = 0;
    auto carve = [&](size_t bytes) {
        void* p = (char*)d_ws + off;
        off += (bytes + 255) & ~(size_t)255;
        return p;
    };
    const size_t sz_t = (size_t)BB * NN * CC * 2;   // one 2B plane = 18.87 MB
    _Float16* xt_hi  = (_Float16*)carve(sz_t);
    _Float16* xt_lo  = (_Float16*)carve(sz_t);
    _Float16* qt_hi  = (_Float16*)carve(sz_t);
    _Float16* qt_lo  = (_Float16*)carve(sz_t);
    _Float16* kt     = (_Float16*)carve(sz_t);
    __hip_bfloat16* vbuf = (__hip_bfloat16*)carve(sz_t);
    _Float16* relhT = (_Float16*)carve((size_t)HH * CC * 2);
    _Float16* relwT = (_Float16*)carve((size_t)HH * CC * 2);
    _Float16* w     = (_Float16*)carve((size_t)3 * CC * CC * 2);
    float* rhq = (float*)carve((size_t)BB * HH * NN * 4);
    float* rwq = (float*)carve((size_t)BB * HH * NN * 4);
    float2* ml = (float2*)carve((size_t)4 * BB * NN * sizeof(float2));
    if (off > ws_size) return;   // base workspace too small -> visible failure

    // split-KV partial planes: 0/1 alias dead xt_hi/xt_lo; 2/3 only if ws fits
    __hip_bfloat16* o0 = (__hip_bfloat16*)xt_hi;
    __hip_bfloat16* o1 = (__hip_bfloat16*)xt_lo;
    __hip_bfloat16* o2 = nullptr;
    __hip_bfloat16* o3 = nullptr;
    int nsplit = 2;
    {
        size_t save = off;
        __hip_bfloat16* p2 = (__hip_bfloat16*)carve(sz_t);
        __hip_bfloat16* p3 = (__hip_bfloat16*)carve(sz_t);
        if (off <= ws_size) { nsplit = 4; o2 = p2; o3 = p3; }
        else { off = save; }
    }
    int tpb = 36 / nsplit;

    k_prep_x<<<dim3(NN / 64, CC / 64, BB), 256, 0, stream>>>(x, xt_hi, xt_lo);
    k_prep_w<<<dim3(3 * CC * CC / 256), 256, 0, stream>>>(Wq, Wk, Wv, w);
    k_prep_rel<<<dim3(HH * CC / 256), 256, 0, stream>>>(rel_h, rel_w, relhT, relwT);
    k_proj<<<dim3(NN / 32, BB, 3), 256, 0, stream>>>(
        xt_hi, xt_lo, w, bq, bk, bv, qt_hi, qt_lo, kt, vbuf);
    k_posq<<<dim3(NN / 64, BB), 256, 0, stream>>>(
        qt_hi, qt_lo, relhT, relwT, rhq, rwq);
    k_attn<<<dim3(NN / 128, BB, nsplit), 512, 0, stream>>>(
        qt_hi, kt, rhq, rwq, vbuf, o0, o1, o2, o3, ml, tpb);
    k_combine<<<dim3((size_t)BB * CC * NN / 1024), 256, 0, stream>>>(
        o0, o1, o2, o3, ml, nsplit, out);
}

// Round 18
// 455.919 us; speedup vs baseline: 1.5902x; 1.0069x over previous
//
#include <hip/hip_runtime.h>
#include <hip/hip_bf16.h>

// MHSA: B=16, C=256, H=W=48, N=2304.
// S[b,n,m] = q[b,:,n]·k[b,:,m] + rhq[b][n%48][m] + rwq[b][n/48][m]
// att = softmax_m(S); out[b,c,n] = sum_m v[b,c,m] att[n,m]
// Numerics: attn S q 1-pass f16 (R17-proven, absmax 0.0625); defer-max THR=8.
// R18: per-tile softmax has NO cross-lane ops in steady state:
//   - lrun kept as per-lane partial, shuffle-reduced ONCE in epilogue
//     (valid: rescale scl is wave-uniform, multiplies all partials equally)
//   - trigger check = 16 per-lane compares + one __any; exact smax chain
//     only on trigger (first tile always triggers -> correct init).

#define BB 16
#define CC 256
#define HH 48
#define NN 2304

typedef float f32x4 __attribute__((ext_vector_type(4)));
typedef short bf16x8 __attribute__((ext_vector_type(8)));
typedef _Float16 f16x8 __attribute__((ext_vector_type(8)));

#define MFMA(a, b, c)  __builtin_amdgcn_mfma_f32_16x16x32_bf16((a), (b), (c), 0, 0, 0)
#define MFMAH(a, b, c) __builtin_amdgcn_mfma_f32_16x16x32_f16((a), (b), (c), 0, 0, 0)

__device__ inline bf16x8 ldg8(const __hip_bfloat16* p) {
    return *reinterpret_cast<const bf16x8*>(p);
}
__device__ inline f16x8 ldh8(const _Float16* p) {
    return *reinterpret_cast<const f16x8*>(p);
}
__device__ inline float bf2f(unsigned short v) {
    unsigned u = (unsigned)v << 16;
    float f;
    __builtin_memcpy(&f, &u, 4);
    return f;
}

typedef __attribute__((address_space(3))) unsigned int lds_uint;
typedef const __attribute__((address_space(1))) unsigned int gbl_uint;

__device__ inline void gload_lds16(const void* g, void* l) {
    __builtin_amdgcn_global_load_lds((gbl_uint*)g, (lds_uint*)l, 16, 0, 0);
}

// ---- prep: transpose x [b][c][n] -> xT [b][n][c], split into f16 hi/lo ----
__global__ __launch_bounds__(256) void k_prep_x(const float* __restrict__ x,
        _Float16* __restrict__ xt_hi, _Float16* __restrict__ xt_lo) {
    __shared__ float tile[64][65];
    int b = blockIdx.z, n0 = blockIdx.x * 64, c0 = blockIdx.y * 64;
    const float* xb = x + (size_t)b * CC * NN;
    #pragma unroll
    for (int i = 0; i < 16; ++i) {
        int idx = i * 256 + threadIdx.x;
        int r = idx >> 6, col = idx & 63;
        tile[r][col] = xb[(size_t)(c0 + r) * NN + n0 + col];
    }
    __syncthreads();
    #pragma unroll
    for (int i = 0; i < 16; ++i) {
        int idx = i * 256 + threadIdx.x;
        int r = idx >> 6, col = idx & 63;           // r = n-local, col = c-local
        float v = tile[col][r];
        _Float16 h = (_Float16)v;
        size_t o = ((size_t)b * NN + n0 + r) * CC + c0 + col;
        xt_hi[o] = h;
        xt_lo[o] = (_Float16)(v - (float)h);
    }
}

// ---- prep: W -> single f16 plane ([3][256][256]) ----
__global__ __launch_bounds__(256) void k_prep_w(const float* __restrict__ Wq,
        const float* __restrict__ Wk, const float* __restrict__ Wv,
        _Float16* __restrict__ w) {
    int i = blockIdx.x * 256 + threadIdx.x;         // < 3*65536
    int m = i >> 16, j = i & 65535;
    const float* W = (m == 0) ? Wq : ((m == 1) ? Wk : Wv);
    w[i] = (_Float16)W[j];
}

// ---- prep: relhT[h][c] = rel_h[c][h] etc, f16 ----
__global__ __launch_bounds__(256) void k_prep_rel(const float* __restrict__ rel_h,
        const float* __restrict__ rel_w,
        _Float16* __restrict__ relhT, _Float16* __restrict__ relwT) {
    int i = blockIdx.x * 256 + threadIdx.x;         // < 48*256
    int h = i >> 8, c = i & 255;
    relhT[i] = (_Float16)rel_h[c * HH + h];
    relwT[i] = (_Float16)rel_w[c * HH + h];
}

// ---- projection GEMM, LDS-staged A (R15) + f16 passes (R16) ----
__global__ __launch_bounds__(256) void k_proj(
        const _Float16* __restrict__ xt_hi, const _Float16* __restrict__ xt_lo,
        const _Float16* __restrict__ w,
        const float* __restrict__ bq, const float* __restrict__ bk, const float* __restrict__ bv,
        _Float16* __restrict__ qt_hi, _Float16* __restrict__ qt_lo,
        _Float16* __restrict__ kt,
        __hip_bfloat16* __restrict__ vbuf) {
    __shared__ __align__(16) _Float16 lds_a[2][32][256];   // [hi/lo][row][c] 32KB
    int b = blockIdx.y, pj = blockIdx.z;
    int n0 = blockIdx.x * 32;
    int wave = threadIdx.x >> 6, lane = threadIdx.x & 63;
    int lr = lane & 15, lg = lane >> 4;
    int o0 = wave * 64;
    const size_t bN = (size_t)b * NN;
    const _Float16* wp = w + (size_t)pj * 65536;

    {
        int r_in = lane >> 5, chunk = lane & 31;
        #pragma unroll
        for (int j = 0; j < 4; ++j) {
            int lrow = wave * 8 + 2 * j;
            int row = lrow + r_in;
            gload_lds16(xt_hi + (bN + n0 + row) * CC + ((chunk ^ (row & 7)) * 8),
                        &lds_a[0][lrow][0]);
            gload_lds16(xt_lo + (bN + n0 + row) * CC + ((chunk ^ (row & 7)) * 8),
                        &lds_a[1][lrow][0]);
        }
    }
    __syncthreads();

    f32x4 acc[2][4] = {};
    #pragma unroll
    for (int ks = 0; ks < 8; ++ks) {
        int kk = ks * 32 + lg * 8;
        f16x8 ah[2], al[2];
        #pragma unroll
        for (int nt = 0; nt < 2; ++nt) {
            int row = nt * 16 + lr;
            int ch = ((ks * 4 + lg) ^ (lr & 7)) * 8;             // swizzled read
            ah[nt] = *reinterpret_cast<const f16x8*>(&lds_a[0][row][ch]);
            al[nt] = *reinterpret_cast<const f16x8*>(&lds_a[1][row][ch]);
        }
        #pragma unroll
        for (int ot = 0; ot < 4; ++ot) {
            int rowB = o0 + ot * 16 + lr;
            f16x8 bh = ldh8(wp + rowB * CC + kk);
            #pragma unroll
            for (int nt = 0; nt < 2; ++nt) {
                acc[nt][ot] = MFMAH(ah[nt], bh, acc[nt][ot]);
                if (pj < 2) acc[nt][ot] = MFMAH(al[nt], bh, acc[nt][ot]);
            }
        }
    }
    const float* bias = (pj == 0) ? bq : ((pj == 1) ? bk : bv);
    #pragma unroll
    for (int ot = 0; ot < 4; ++ot) {
        int o = o0 + ot * 16 + lr;
        float bb = bias[o];
        #pragma unroll
        for (int nt = 0; nt < 2; ++nt) {
            #pragma unroll
            for (int r = 0; r < 4; ++r) {
                int n = n0 + nt * 16 + lg * 4 + r;
                float y = acc[nt][ot][r] + bb;
                if (pj == 0) {
                    _Float16 h = (_Float16)y;
                    size_t off = (bN + n) * CC + o;
                    qt_hi[off] = h;
                    qt_lo[off] = (_Float16)(y - (float)h);
                } else if (pj == 1) {
                    kt[(bN + n) * CC + o] = (_Float16)y;
                } else {
                    vbuf[((size_t)b * CC + o) * NN + n] = __float2bfloat16(y);
                }
            }
        }
    }
}

// ---- pos rank-split (f16 2-pass, 2-plane q): rhq = relhT q, rwq = relwT q ---
__global__ __launch_bounds__(256) void k_posq(
        const _Float16* __restrict__ qt_hi, const _Float16* __restrict__ qt_lo,
        const _Float16* __restrict__ relhT, const _Float16* __restrict__ relwT,
        float* __restrict__ rhq, float* __restrict__ rwq) {
    int b = blockIdx.y, m0 = blockIdx.x * 64;
    int wave = threadIdx.x >> 6, lane = threadIdx.x & 63;
    int lr = lane & 15, lg = lane >> 4;
    int m = m0 + wave * 16 + lr;                    // output column
    const size_t bN = (size_t)b * NN;
    f32x4 acc[6] = {};                              // 3 h-tiles rh, 3 w-tiles rw
    #pragma unroll
    for (int ks = 0; ks < 8; ++ks) {
        int kk = ks * 32 + lg * 8;
        f16x8 bhf = ldh8(qt_hi + (bN + m) * CC + kk);
        f16x8 blf = ldh8(qt_lo + (bN + m) * CC + kk);
        #pragma unroll
        for (int t = 0; t < 3; ++t) {
            int rowH = t * 16 + lr;
            f16x8 ahh = ldh8(relhT + rowH * CC + kk);
            acc[t] = MFMAH(ahh, bhf, acc[t]);
            acc[t] = MFMAH(ahh, blf, acc[t]);
            f16x8 awh = ldh8(relwT + rowH * CC + kk);
            acc[3 + t] = MFMAH(awh, bhf, acc[3 + t]);
            acc[3 + t] = MFMAH(awh, blf, acc[3 + t]);
        }
    }
    #pragma unroll
    for (int t = 0; t < 3; ++t) {
        #pragma unroll
        for (int r = 0; r < 4; ++r) {
            int h = t * 16 + lg * 4 + r;
            rhq[((size_t)b * HH + h) * NN + m] = acc[t][r];
            rwq[((size_t)b * HH + h) * NN + m] = acc[3 + t][r];
        }
    }
}

// ---- flash attention, split-KV, shuffle-free steady-state softmax (R18) ----
__global__ __launch_bounds__(512, 2) void k_attn(
        const _Float16* __restrict__ qt_hi,
        const _Float16* __restrict__ kt,
        const float* __restrict__ rhq, const float* __restrict__ rwq,
        const __hip_bfloat16* __restrict__ vbuf,
        __hip_bfloat16* __restrict__ o0, __hip_bfloat16* __restrict__ o1,
        __hip_bfloat16* __restrict__ o2, __hip_bfloat16* __restrict__ o3,
        float2* __restrict__ ml, int tpb) {
    __shared__ __align__(16) _Float16 lds_k[2][64][128];          // [slice][row][k] 32KB
    __shared__ __align__(16) __hip_bfloat16 lds_v[256][64];       // [c][m] 32KB (swizzled)
    __shared__ __align__(16) __hip_bfloat16 lds_p[128][64];       // shared P tile 16KB (swizzled)
    // scale + votes aliased into buf1 (staged over each tile; rewritten
    // before every use -> deterministic).
    float* lds_scale = reinterpret_cast<float*>(&lds_k[1][0][0]);
    int*   lds_flag  = reinterpret_cast<int*>(lds_scale + 128);   // [8]
    int b = blockIdx.y;
    int n0 = blockIdx.x * 128;
    int z = blockIdx.z;
    int t0 = z * tpb, t_end = t0 + tpb;
    __hip_bfloat16* opart = (z == 0) ? o0 : (z == 1) ? o1 : (z == 2) ? o2 : o3;
    int wave = threadIdx.x >> 6, lane = threadIdx.x & 63;
    int lr = lane & 15, lg = lane >> 4;
    int rowA = n0 + wave * 16 + lr;
    const size_t bN = (size_t)b * NN;

    f16x8 qh[8];
    #pragma unroll
    for (int ks = 0; ks < 8; ++ks) {
        int kk = ks * 32 + lg * 8;
        qh[ks] = ldh8(qt_hi + (bN + rowA) * CC + kk);
    }
    int hn[4], wn[4];
    #pragma unroll
    for (int r = 0; r < 4; ++r) {
        int n = n0 + wave * 16 + lg * 4 + r;
        hn[r] = n % HH;
        wn[r] = n / HH;
    }
    const float* rhq_b = rhq + (size_t)b * HH * NN;
    const float* rwq_b = rwq + (size_t)b * HH * NN;

    int nh = wave >> 2;                 // n-half
    int cq = wave & 3;                  // c-quarter
    f32x4 oacc[4][4] = {};              // [nf][cf]
    float mrun[4] = {-1e30f, -1e30f, -1e30f, -1e30f};
    float lrun[4] = {0.f, 0.f, 0.f, 0.f};   // PER-LANE partial (reduced in epilogue)

    // K staging ([64][128] f16, 256B rows, 16 chunks): per call 4 rows.
    int krin = lane >> 4, kch = lane & 15;
    auto STAGE_K = [&](int buf, int m0s, int k0) {
        #pragma unroll
        for (int j = 0; j < 2; ++j) {
            int lrow = wave * 8 + j * 4;
            int grow = lrow + krin;
            gload_lds16(kt + (bN + m0s + grow) * CC + k0 + ((kch ^ (grow & 7)) * 8),
                        &lds_k[buf][lrow][0]);
        }
    };
    // V staging ([256][64] bf16, 128B rows, 8 chunks): half (128 c-rows) per phase.
    int srl = lane >> 3;
    int sch = ((lane & 7) ^ srl) * 8;
    auto STAGE_V = [&](int half, int m0s) {
        #pragma unroll
        for (int j = 0; j < 2; ++j) {
            int lrow = half * 128 + wave * 16 + j * 8;
            int crow = lrow + srl;
            gload_lds16(vbuf + ((size_t)b * CC + crow) * NN + m0s + sch, &lds_v[lrow][0]);
        }
    };

    STAGE_K(0, t0 * 64, 0);
    __syncthreads();

    for (int t = t0; t < t_end; ++t) {
        int m0 = t * 64;
        float padd[4][4];
        #pragma unroll
        for (int mt = 0; mt < 4; ++mt) {
            int m = m0 + mt * 16 + lr;
            #pragma unroll
            for (int r = 0; r < 4; ++r)
                padd[mt][r] = rhq_b[(size_t)hn[r] * NN + m] + rwq_b[(size_t)wn[r] * NN + m];
        }
        f32x4 sacc[4] = {};
        #pragma unroll
        for (int s = 0; s < 2; ++s) {
            if (s == 0) {
                STAGE_K(1, m0, 128);                  // slice1 of current tile
                STAGE_V(0, m0);
            } else {
                int mn = (t + 1 < t_end) ? (t + 1) * 64 : t0 * 64;
                STAGE_K(0, mn, 0);                    // next tile slice0
                STAGE_V(1, m0);
            }
            #pragma unroll
            for (int ks = 0; ks < 4; ++ks) {
                #pragma unroll
                for (int mt = 0; mt < 4; ++mt) {
                    int row = mt * 16 + lr;
                    int ch = ((ks * 4 + lg) ^ (lr & 7)) * 8;      // swizzled read
                    f16x8 bh = *reinterpret_cast<const f16x8*>(&lds_k[s][row][ch]);
                    sacc[mt] = MFMAH(qh[s * 4 + ks], bh, sacc[mt]);
                }
            }
            __syncthreads();
        }
        #pragma unroll
        for (int mt = 0; mt < 4; ++mt)
            #pragma unroll
            for (int r = 0; r < 4; ++r)
                sacc[mt][r] += padd[mt][r];
        // ---- softmax: cheap trigger check, shuffle-free common path ----
        bool lane_need = false;
        #pragma unroll
        for (int mt = 0; mt < 4; ++mt)
            #pragma unroll
            for (int r = 0; r < 4; ++r)
                lane_need |= (sacc[mt][r] > mrun[r] + 8.0f);
        bool wave_need = __any(lane_need);            // wave-uniform branch
        float scl_r[4] = {1.f, 1.f, 1.f, 1.f};
        if (wave_need) {
            #pragma unroll
            for (int r = 0; r < 4; ++r) {
                float smax = fmaxf(fmaxf(sacc[0][r], sacc[1][r]),
                                   fmaxf(sacc[2][r], sacc[3][r]));
                #pragma unroll
                for (int mk = 1; mk <= 8; mk <<= 1)
                    smax = fmaxf(smax, __shfl_xor(smax, mk));
                float mnew = fmaxf(mrun[r], smax);
                scl_r[r] = __expf(mrun[r] - mnew);    // exp(-inf)=0 on first tile
                mrun[r] = mnew;
                lrun[r] *= scl_r[r];
            }
        }
        #pragma unroll
        for (int r = 0; r < 4; ++r) {
            float rsum = 0.f;
            #pragma unroll
            for (int mt = 0; mt < 4; ++mt) {
                float p = __expf(sacc[mt][r] - mrun[r]);   // bounded by e^8
                sacc[mt][r] = p;
                rsum += p;
            }
            lrun[r] += rsum;                          // per-lane partial only
        }
        // ---- P + scale + vote -> LDS ----
        #pragma unroll
        for (int mt = 0; mt < 4; ++mt) {
            #pragma unroll
            for (int r = 0; r < 4; ++r) {
                int prow = wave * 16 + lg * 4 + r;
                int pcol = mt * 16 + lr;
                int pcol_s = (((pcol >> 3) ^ (prow & 7)) << 3) | (pcol & 7);
                lds_p[prow][pcol_s] = __float2bfloat16(sacc[mt][r]);
            }
        }
        if (lr == 0) {
            #pragma unroll
            for (int r = 0; r < 4; ++r)
                lds_scale[wave * 16 + lg * 4 + r] = scl_r[r];
        }
        if (lane == 0) lds_flag[wave] = wave_need ? 1 : 0;
        __syncthreads();
        // ---- PV: rescale only if any wave voted ----
        int4 f0 = *reinterpret_cast<const int4*>(&lds_flag[0]);
        int4 f1 = *reinterpret_cast<const int4*>(&lds_flag[4]);
        bool do_scale = (f0.x | f0.y | f0.z | f0.w | f1.x | f1.y | f1.z | f1.w) != 0;
        if (do_scale) {
            #pragma unroll
            for (int nf = 0; nf < 4; ++nf) {
                f32x4 s4 = *reinterpret_cast<const f32x4*>(&lds_scale[nh * 64 + nf * 16 + lg * 4]);
                #pragma unroll
                for (int cf = 0; cf < 4; ++cf)
                    oacc[nf][cf] *= s4;
            }
        }
        #pragma unroll
        for (int ks2 = 0; ks2 < 2; ++ks2) {
            bf16x8 pa[4];
            #pragma unroll
            for (int nf = 0; nf < 4; ++nf) {
                int prow = nh * 64 + nf * 16 + lr;
                int pch = ((ks2 * 4 + lg) ^ (lr & 7)) * 8;
                pa[nf] = *reinterpret_cast<const bf16x8*>(&lds_p[prow][pch]);
            }
            #pragma unroll
            for (int cf = 0; cf < 4; ++cf) {
                int vrow = cq * 64 + cf * 16 + lr;
                int vch = ((ks2 * 4 + lg) ^ (lr & 7)) * 8;
                bf16x8 bv = *reinterpret_cast<const bf16x8*>(&lds_v[vrow][vch]);
                #pragma unroll
                for (int nf = 0; nf < 4; ++nf)
                    oacc[nf][cf] = MFMA(pa[nf], bv, oacc[nf][cf]);
            }
        }
        __syncthreads();
    }
    // ---- epilogue: reduce lrun partials across the 16-lane row group ----
    #pragma unroll
    for (int r = 0; r < 4; ++r) {
        #pragma unroll
        for (int mk = 1; mk <= 8; mk <<= 1)
            lrun[r] += __shfl_xor(lrun[r], mk);
    }
    if (lr == 0) {
        #pragma unroll
        for (int r = 0; r < 4; ++r) {
            int n = n0 + wave * 16 + lg * 4 + r;
            ml[((size_t)z * BB + b) * NN + n] = make_float2(mrun[r], lrun[r]);
        }
    }
    #pragma unroll
    for (int nf = 0; nf < 4; ++nf) {
        int nbase = n0 + nh * 64 + nf * 16 + lg * 4;
        #pragma unroll
        for (int cf = 0; cf < 4; ++cf) {
            int c = cq * 64 + cf * 16 + lr;
            union { ushort4 u4; unsigned short us[4]; } pk;
            #pragma unroll
            for (int j = 0; j < 4; ++j) {
                __hip_bfloat16 hv = __float2bfloat16(oacc[nf][cf][j]);
                pk.us[j] = *reinterpret_cast<unsigned short*>(&hv);
            }
            *reinterpret_cast<ushort4*>(&opart[((size_t)b * CC + c) * NN + nbase]) = pk.u4;
        }
    }
}

// ---- combine: out[b][c][n] = sum_z o_z*exp(m_z-M) / sum_z l_z*exp(m_z-M) ----
__global__ __launch_bounds__(256) void k_combine(
        const __hip_bfloat16* __restrict__ o0, const __hip_bfloat16* __restrict__ o1,
        const __hip_bfloat16* __restrict__ o2, const __hip_bfloat16* __restrict__ o3,
        const float2* __restrict__ ml, int nsplit, float* __restrict__ out) {
    size_t idx = ((size_t)blockIdx.x * 256 + threadIdx.x) * 4;   // over B*CC*NN
    int n4 = (int)(idx % NN);
    int c  = (int)((idx / NN) % CC);
    int b  = (int)(idx / ((size_t)NN * CC));
    float M[4] = {-1e30f, -1e30f, -1e30f, -1e30f};
    for (int zz = 0; zz < nsplit; ++zz) {
        #pragma unroll
        for (int j = 0; j < 4; ++j)
            M[j] = fmaxf(M[j], ml[((size_t)zz * BB + b) * NN + n4 + j].x);
    }
    float num[4] = {}, den[4] = {};
    for (int zz = 0; zz < nsplit; ++zz) {
        const __hip_bfloat16* op = (zz == 0) ? o0 : (zz == 1) ? o1 : (zz == 2) ? o2 : o3;
        ushort4 u = *reinterpret_cast<const ushort4*>(op + ((size_t)b * CC + c) * NN + n4);
        unsigned short us[4] = {u.x, u.y, u.z, u.w};
        #pragma unroll
        for (int j = 0; j < 4; ++j) {
            float2 v = ml[((size_t)zz * BB + b) * NN + n4 + j];
            float w = __expf(v.x - M[j]);
            num[j] += bf2f(us[j]) * w;
            den[j] += v.y * w;
        }
    }
    f32x4 o;
    #pragma unroll
    for (int j = 0; j < 4; ++j) o[j] = num[j] / den[j];
    *reinterpret_cast<f32x4*>(&out[idx]) = o;
}

extern "C" void kernel_launch(void* const* d_in, const int* in_sizes, int n_in,
                              void* d_out, int out_size, void* d_ws, size_t ws_size,
                              hipStream_t stream) {
    const float* x     = (const float*)d_in[0];
    const float* Wq    = (const float*)d_in[1];
    const float* bq    = (const float*)d_in[2];
    const float* Wk    = (const float*)d_in[3];
    const float* bk    = (const float*)d_in[4];
    const float* Wv    = (const float*)d_in[5];
    const float* bv    = (const float*)d_in[6];
    const float* rel_h = (const float*)d_in[7];
    const float* rel_w = (const float*)d_in[8];
    float* out = (float*)d_out;

    size_t off = 0;
    auto carve = [&](size_t bytes) {
        void* p = (char*)d_ws + off;
        off += (bytes + 255) & ~(size_t)255;
        return p;
    };
    const size_t sz_t = (size_t)BB * NN * CC * 2;   // one 2B plane = 18.87 MB
    _Float16* xt_hi  = (_Float16*)carve(sz_t);
    _Float16* xt_lo  = (_Float16*)carve(sz_t);
    _Float16* qt_hi  = (_Float16*)carve(sz_t);
    _Float16* qt_lo  = (_Float16*)carve(sz_t);
    _Float16* kt     = (_Float16*)carve(sz_t);
    __hip_bfloat16* vbuf = (__hip_bfloat16*)carve(sz_t);
    _Float16* relhT = (_Float16*)carve((size_t)HH * CC * 2);
    _Float16* relwT = (_Float16*)carve((size_t)HH * CC * 2);
    _Float16* w     = (_Float16*)carve((size_t)3 * CC * CC * 2);
    float* rhq = (float*)carve((size_t)BB * HH * NN * 4);
    float* rwq = (float*)carve((size_t)BB * HH * NN * 4);
    float2* ml = (float2*)carve((size_t)4 * BB * NN * sizeof(float2));
    if (off > ws_size) return;   // base workspace too small -> visible failure

    // split-KV partial planes: 0/1 alias dead xt_hi/xt_lo; 2/3 only if ws fits
    __hip_bfloat16* o0 = (__hip_bfloat16*)xt_hi;
    __hip_bfloat16* o1 = (__hip_bfloat16*)xt_lo;
    __hip_bfloat16* o2 = nullptr;
    __hip_bfloat16* o3 = nullptr;
    int nsplit = 2;
    {
        size_t save = off;
        __hip_bfloat16* p2 = (__hip_bfloat16*)carve(sz_t);
        __hip_bfloat16* p3 = (__hip_bfloat16*)carve(sz_t);
        if (off <= ws_size) { nsplit = 4; o2 = p2; o3 = p3; }
        else { off = save; }
    }
    int tpb = 36 / nsplit;

    k_prep_x<<<dim3(NN / 64, CC / 64, BB), 256, 0, stream>>>(x, xt_hi, xt_lo);
    k_prep_w<<<dim3(3 * CC * CC / 256), 256, 0, stream>>>(Wq, Wk, Wv, w);
    k_prep_rel<<<dim3(HH * CC / 256), 256, 0, stream>>>(rel_h, rel_w, relhT, relwT);
    k_proj<<<dim3(NN / 32, BB, 3), 256, 0, stream>>>(
        xt_hi, xt_lo, w, bq, bk, bv, qt_hi, qt_lo, kt, vbuf);
    k_posq<<<dim3(NN / 64, BB), 256, 0, stream>>>(
        qt_hi, qt_lo, relhT, relwT, rhq, rwq);
    k_attn<<<dim3(NN / 128, BB, nsplit), 512, 0, stream>>>(
        qt_hi, kt, rhq, rwq, vbuf, o0, o1, o2, o3, ml, tpb);
    k_combine<<<dim3((size_t)BB * CC * NN / 1024), 256, 0, stream>>>(
        o0, o1, o2, o3, ml, nsplit, out);
}

// Round 19
// 444.828 us; speedup vs baseline: 1.6298x; 1.0249x over previous
//
#include <hip/hip_runtime.h>
#include <hip/hip_bf16.h>

// MHSA: B=16, C=256, H=W=48, N=2304.
// S[b,n,m] = q[b,:,n]·k[b,:,m] + rhq[b][n%48][m] + rwq[b][n/48][m]
// att = softmax_m(S); out[b,c,n] = sum_m v[b,c,m] att[n,m]
// Numerics: attn S q 1-pass f16, defer-max THR=8 (R17/R18-proven, 0.0625).
// R19: prep_x fused into unified QKV proj — x read ONCE per n-slice
// (f32 LDS-transpose tile, +1 pad), split to f16 hi/lo written directly in
// the XOR-swizzled layout; 3 pj-GEMMs reuse the staged A-tile. Removes the
// xt intermediate (75MB write + 226MB re-read -> 151MB x read).

#define BB 16
#define CC 256
#define HH 48
#define NN 2304

typedef float f32x4 __attribute__((ext_vector_type(4)));
typedef short bf16x8 __attribute__((ext_vector_type(8)));
typedef _Float16 f16x8 __attribute__((ext_vector_type(8)));

#define MFMA(a, b, c)  __builtin_amdgcn_mfma_f32_16x16x32_bf16((a), (b), (c), 0, 0, 0)
#define MFMAH(a, b, c) __builtin_amdgcn_mfma_f32_16x16x32_f16((a), (b), (c), 0, 0, 0)

__device__ inline bf16x8 ldg8(const __hip_bfloat16* p) {
    return *reinterpret_cast<const bf16x8*>(p);
}
__device__ inline f16x8 ldh8(const _Float16* p) {
    return *reinterpret_cast<const f16x8*>(p);
}
__device__ inline float bf2f(unsigned short v) {
    unsigned u = (unsigned)v << 16;
    float f;
    __builtin_memcpy(&f, &u, 4);
    return f;
}

typedef __attribute__((address_space(3))) unsigned int lds_uint;
typedef const __attribute__((address_space(1))) unsigned int gbl_uint;

__device__ inline void gload_lds16(const void* g, void* l) {
    __builtin_amdgcn_global_load_lds((gbl_uint*)g, (lds_uint*)l, 16, 0, 0);
}

// ---- prep: W -> single f16 plane ([3][256][256]) ----
__global__ __launch_bounds__(256) void k_prep_w(const float* __restrict__ Wq,
        const float* __restrict__ Wk, const float* __restrict__ Wv,
        _Float16* __restrict__ w) {
    int i = blockIdx.x * 256 + threadIdx.x;         // < 3*65536
    int m = i >> 16, j = i & 65535;
    const float* W = (m == 0) ? Wq : ((m == 1) ? Wk : Wv);
    w[i] = (_Float16)W[j];
}

// ---- prep: relhT[h][c] = rel_h[c][h] etc, f16 ----
__global__ __launch_bounds__(256) void k_prep_rel(const float* __restrict__ rel_h,
        const float* __restrict__ rel_w,
        _Float16* __restrict__ relhT, _Float16* __restrict__ relwT) {
    int i = blockIdx.x * 256 + threadIdx.x;         // < 48*256
    int h = i >> 8, c = i & 255;
    relhT[i] = (_Float16)rel_h[c * HH + h];
    relwT[i] = (_Float16)rel_w[c * HH + h];
}

// ---- unified QKV projection (R19): block = 32 n-rows x ALL 3 projections ----
// grid (72, 16); 4 waves, wave owns o-slice [wave*64, wave*64+64).
// Stage: x[b][:][n0..n0+31] -> f32 LDS transpose tile (+1 pad, conflict-free)
// -> split f16 hi/lo written in XOR-swizzled layout (phys chunk = c>>3 ^ r&7).
// Then 3 pj-GEMMs over the same A-tile: q 2-pass, k 2-pass, v 1-pass.
__global__ __launch_bounds__(256) void k_projqkv(
        const float* __restrict__ x,
        const _Float16* __restrict__ w,
        const float* __restrict__ bq, const float* __restrict__ bk, const float* __restrict__ bv,
        _Float16* __restrict__ qt_hi, _Float16* __restrict__ qt_lo,
        _Float16* __restrict__ kt,
        __hip_bfloat16* __restrict__ vbuf) {
    __shared__ float xf[32][257];                          // 32.9KB transpose tile
    __shared__ __align__(16) _Float16 lds_a[2][32][256];   // [hi/lo][row][c] 32KB swizzled
    int b = blockIdx.y;
    int n0 = blockIdx.x * 32;
    int t = threadIdx.x;
    int wave = t >> 6, lane = t & 63;
    int lr = lane & 15, lg = lane >> 4;
    int o0 = wave * 64;
    const size_t bN = (size_t)b * NN;

    // load x (coalesced 128B per c-row, 8 rows/iter) into f32 tile
    {
        int nj = t & 31, cg = t >> 5;
        #pragma unroll
        for (int it = 0; it < 32; ++it) {
            int c = it * 8 + cg;
            xf[nj][c] = x[((size_t)b * CC + c) * NN + n0 + nj];
        }
    }
    __syncthreads();
    // split to f16 hi/lo, write swizzled (read banks conflict-free via pad)
    {
        int r = t & 31, cg = t >> 5;
        #pragma unroll
        for (int i = 0; i < 32; ++i) {
            int c = cg + 8 * i;
            float v = xf[r][c];
            _Float16 h = (_Float16)v;
            int pc = (((c >> 3) ^ (r & 7)) << 3) | (c & 7);
            lds_a[0][r][pc] = h;
            lds_a[1][r][pc] = (_Float16)(v - (float)h);
        }
    }
    __syncthreads();

    #pragma unroll
    for (int pj = 0; pj < 3; ++pj) {
        const _Float16* wp = w + (size_t)pj * 65536;
        f32x4 acc[2][4] = {};
        #pragma unroll
        for (int ks = 0; ks < 8; ++ks) {
            int kk = ks * 32 + lg * 8;
            f16x8 ah[2], al[2];
            #pragma unroll
            for (int nt = 0; nt < 2; ++nt) {
                int row = nt * 16 + lr;
                int ch = ((ks * 4 + lg) ^ (lr & 7)) * 8;   // swizzled read
                ah[nt] = *reinterpret_cast<const f16x8*>(&lds_a[0][row][ch]);
                al[nt] = *reinterpret_cast<const f16x8*>(&lds_a[1][row][ch]);
            }
            #pragma unroll
            for (int ot = 0; ot < 4; ++ot) {
                int rowB = o0 + ot * 16 + lr;
                f16x8 bh = ldh8(wp + rowB * CC + kk);
                #pragma unroll
                for (int nt = 0; nt < 2; ++nt) {
                    acc[nt][ot] = MFMAH(ah[nt], bh, acc[nt][ot]);
                    if (pj < 2) acc[nt][ot] = MFMAH(al[nt], bh, acc[nt][ot]);
                }
            }
        }
        const float* bias = (pj == 0) ? bq : ((pj == 1) ? bk : bv);
        #pragma unroll
        for (int ot = 0; ot < 4; ++ot) {
            int o = o0 + ot * 16 + lr;
            float bb = bias[o];
            #pragma unroll
            for (int nt = 0; nt < 2; ++nt) {
                #pragma unroll
                for (int r = 0; r < 4; ++r) {
                    int n = n0 + nt * 16 + lg * 4 + r;
                    float y = acc[nt][ot][r] + bb;
                    if (pj == 0) {
                        _Float16 h = (_Float16)y;
                        size_t off = (bN + n) * CC + o;
                        qt_hi[off] = h;
                        qt_lo[off] = (_Float16)(y - (float)h);
                    } else if (pj == 1) {
                        kt[(bN + n) * CC + o] = (_Float16)y;
                    } else {
                        vbuf[((size_t)b * CC + o) * NN + n] = __float2bfloat16(y);
                    }
                }
            }
        }
    }
}

// ---- pos rank-split (f16 2-pass, 2-plane q): rhq = relhT q, rwq = relwT q ---
__global__ __launch_bounds__(256) void k_posq(
        const _Float16* __restrict__ qt_hi, const _Float16* __restrict__ qt_lo,
        const _Float16* __restrict__ relhT, const _Float16* __restrict__ relwT,
        float* __restrict__ rhq, float* __restrict__ rwq) {
    int b = blockIdx.y, m0 = blockIdx.x * 64;
    int wave = threadIdx.x >> 6, lane = threadIdx.x & 63;
    int lr = lane & 15, lg = lane >> 4;
    int m = m0 + wave * 16 + lr;                    // output column
    const size_t bN = (size_t)b * NN;
    f32x4 acc[6] = {};                              // 3 h-tiles rh, 3 w-tiles rw
    #pragma unroll
    for (int ks = 0; ks < 8; ++ks) {
        int kk = ks * 32 + lg * 8;
        f16x8 bhf = ldh8(qt_hi + (bN + m) * CC + kk);
        f16x8 blf = ldh8(qt_lo + (bN + m) * CC + kk);
        #pragma unroll
        for (int t = 0; t < 3; ++t) {
            int rowH = t * 16 + lr;
            f16x8 ahh = ldh8(relhT + rowH * CC + kk);
            acc[t] = MFMAH(ahh, bhf, acc[t]);
            acc[t] = MFMAH(ahh, blf, acc[t]);
            f16x8 awh = ldh8(relwT + rowH * CC + kk);
            acc[3 + t] = MFMAH(awh, bhf, acc[3 + t]);
            acc[3 + t] = MFMAH(awh, blf, acc[3 + t]);
        }
    }
    #pragma unroll
    for (int t = 0; t < 3; ++t) {
        #pragma unroll
        for (int r = 0; r < 4; ++r) {
            int h = t * 16 + lg * 4 + r;
            rhq[((size_t)b * HH + h) * NN + m] = acc[t][r];
            rwq[((size_t)b * HH + h) * NN + m] = acc[3 + t][r];
        }
    }
}

// ---- flash attention, split-KV, shuffle-free steady-state softmax (R18) ----
__global__ __launch_bounds__(512, 2) void k_attn(
        const _Float16* __restrict__ qt_hi,
        const _Float16* __restrict__ kt,
        const float* __restrict__ rhq, const float* __restrict__ rwq,
        const __hip_bfloat16* __restrict__ vbuf,
        __hip_bfloat16* __restrict__ o0, __hip_bfloat16* __restrict__ o1,
        __hip_bfloat16* __restrict__ o2, __hip_bfloat16* __restrict__ o3,
        float2* __restrict__ ml, int tpb) {
    __shared__ __align__(16) _Float16 lds_k[2][64][128];          // [slice][row][k] 32KB
    __shared__ __align__(16) __hip_bfloat16 lds_v[256][64];       // [c][m] 32KB (swizzled)
    __shared__ __align__(16) __hip_bfloat16 lds_p[128][64];       // shared P tile 16KB (swizzled)
    float* lds_scale = reinterpret_cast<float*>(&lds_k[1][0][0]);
    int*   lds_flag  = reinterpret_cast<int*>(lds_scale + 128);   // [8]
    int b = blockIdx.y;
    int n0 = blockIdx.x * 128;
    int z = blockIdx.z;
    int t0 = z * tpb, t_end = t0 + tpb;
    __hip_bfloat16* opart = (z == 0) ? o0 : (z == 1) ? o1 : (z == 2) ? o2 : o3;
    int wave = threadIdx.x >> 6, lane = threadIdx.x & 63;
    int lr = lane & 15, lg = lane >> 4;
    int rowA = n0 + wave * 16 + lr;
    const size_t bN = (size_t)b * NN;

    f16x8 qh[8];
    #pragma unroll
    for (int ks = 0; ks < 8; ++ks) {
        int kk = ks * 32 + lg * 8;
        qh[ks] = ldh8(qt_hi + (bN + rowA) * CC + kk);
    }
    int hn[4], wn[4];
    #pragma unroll
    for (int r = 0; r < 4; ++r) {
        int n = n0 + wave * 16 + lg * 4 + r;
        hn[r] = n % HH;
        wn[r] = n / HH;
    }
    const float* rhq_b = rhq + (size_t)b * HH * NN;
    const float* rwq_b = rwq + (size_t)b * HH * NN;

    int nh = wave >> 2;                 // n-half
    int cq = wave & 3;                  // c-quarter
    f32x4 oacc[4][4] = {};              // [nf][cf]
    float mrun[4] = {-1e30f, -1e30f, -1e30f, -1e30f};
    float lrun[4] = {0.f, 0.f, 0.f, 0.f};   // per-lane partial (epilogue-reduced)

    int krin = lane >> 4, kch = lane & 15;
    auto STAGE_K = [&](int buf, int m0s, int k0) {
        #pragma unroll
        for (int j = 0; j < 2; ++j) {
            int lrow = wave * 8 + j * 4;
            int grow = lrow + krin;
            gload_lds16(kt + (bN + m0s + grow) * CC + k0 + ((kch ^ (grow & 7)) * 8),
                        &lds_k[buf][lrow][0]);
        }
    };
    int srl = lane >> 3;
    int sch = ((lane & 7) ^ srl) * 8;
    auto STAGE_V = [&](int half, int m0s) {
        #pragma unroll
        for (int j = 0; j < 2; ++j) {
            int lrow = half * 128 + wave * 16 + j * 8;
            int crow = lrow + srl;
            gload_lds16(vbuf + ((size_t)b * CC + crow) * NN + m0s + sch, &lds_v[lrow][0]);
        }
    };

    STAGE_K(0, t0 * 64, 0);
    __syncthreads();

    for (int t = t0; t < t_end; ++t) {
        int m0 = t * 64;
        float padd[4][4];
        #pragma unroll
        for (int mt = 0; mt < 4; ++mt) {
            int m = m0 + mt * 16 + lr;
            #pragma unroll
            for (int r = 0; r < 4; ++r)
                padd[mt][r] = rhq_b[(size_t)hn[r] * NN + m] + rwq_b[(size_t)wn[r] * NN + m];
        }
        f32x4 sacc[4] = {};
        #pragma unroll
        for (int s = 0; s < 2; ++s) {
            if (s == 0) {
                STAGE_K(1, m0, 128);
                STAGE_V(0, m0);
            } else {
                int mn = (t + 1 < t_end) ? (t + 1) * 64 : t0 * 64;
                STAGE_K(0, mn, 0);
                STAGE_V(1, m0);
            }
            #pragma unroll
            for (int ks = 0; ks < 4; ++ks) {
                #pragma unroll
                for (int mt = 0; mt < 4; ++mt) {
                    int row = mt * 16 + lr;
                    int ch = ((ks * 4 + lg) ^ (lr & 7)) * 8;
                    f16x8 bh = *reinterpret_cast<const f16x8*>(&lds_k[s][row][ch]);
                    sacc[mt] = MFMAH(qh[s * 4 + ks], bh, sacc[mt]);
                }
            }
            __syncthreads();
        }
        #pragma unroll
        for (int mt = 0; mt < 4; ++mt)
            #pragma unroll
            for (int r = 0; r < 4; ++r)
                sacc[mt][r] += padd[mt][r];
        // softmax: cheap trigger, shuffle-free common path
        bool lane_need = false;
        #pragma unroll
        for (int mt = 0; mt < 4; ++mt)
            #pragma unroll
            for (int r = 0; r < 4; ++r)
                lane_need |= (sacc[mt][r] > mrun[r] + 8.0f);
        bool wave_need = __any(lane_need);
        float scl_r[4] = {1.f, 1.f, 1.f, 1.f};
        if (wave_need) {
            #pragma unroll
            for (int r = 0; r < 4; ++r) {
                float smax = fmaxf(fmaxf(sacc[0][r], sacc[1][r]),
                                   fmaxf(sacc[2][r], sacc[3][r]));
                #pragma unroll
                for (int mk = 1; mk <= 8; mk <<= 1)
                    smax = fmaxf(smax, __shfl_xor(smax, mk));
                float mnew = fmaxf(mrun[r], smax);
                scl_r[r] = __expf(mrun[r] - mnew);
                mrun[r] = mnew;
                lrun[r] *= scl_r[r];
            }
        }
        #pragma unroll
        for (int r = 0; r < 4; ++r) {
            float rsum = 0.f;
            #pragma unroll
            for (int mt = 0; mt < 4; ++mt) {
                float p = __expf(sacc[mt][r] - mrun[r]);
                sacc[mt][r] = p;
                rsum += p;
            }
            lrun[r] += rsum;
        }
        #pragma unroll
        for (int mt = 0; mt < 4; ++mt) {
            #pragma unroll
            for (int r = 0; r < 4; ++r) {
                int prow = wave * 16 + lg * 4 + r;
                int pcol = mt * 16 + lr;
                int pcol_s = (((pcol >> 3) ^ (prow & 7)) << 3) | (pcol & 7);
                lds_p[prow][pcol_s] = __float2bfloat16(sacc[mt][r]);
            }
        }
        if (lr == 0) {
            #pragma unroll
            for (int r = 0; r < 4; ++r)
                lds_scale[wave * 16 + lg * 4 + r] = scl_r[r];
        }
        if (lane == 0) lds_flag[wave] = wave_need ? 1 : 0;
        __syncthreads();
        int4 f0 = *reinterpret_cast<const int4*>(&lds_flag[0]);
        int4 f1 = *reinterpret_cast<const int4*>(&lds_flag[4]);
        bool do_scale = (f0.x | f0.y | f0.z | f0.w | f1.x | f1.y | f1.z | f1.w) != 0;
        if (do_scale) {
            #pragma unroll
            for (int nf = 0; nf < 4; ++nf) {
                f32x4 s4 = *reinterpret_cast<const f32x4*>(&lds_scale[nh * 64 + nf * 16 + lg * 4]);
                #pragma unroll
                for (int cf = 0; cf < 4; ++cf)
                    oacc[nf][cf] *= s4;
            }
        }
        #pragma unroll
        for (int ks2 = 0; ks2 < 2; ++ks2) {
            bf16x8 pa[4];
            #pragma unroll
            for (int nf = 0; nf < 4; ++nf) {
                int prow = nh * 64 + nf * 16 + lr;
                int pch = ((ks2 * 4 + lg) ^ (lr & 7)) * 8;
                pa[nf] = *reinterpret_cast<const bf16x8*>(&lds_p[prow][pch]);
            }
            #pragma unroll
            for (int cf = 0; cf < 4; ++cf) {
                int vrow = cq * 64 + cf * 16 + lr;
                int vch = ((ks2 * 4 + lg) ^ (lr & 7)) * 8;
                bf16x8 bv = *reinterpret_cast<const bf16x8*>(&lds_v[vrow][vch]);
                #pragma unroll
                for (int nf = 0; nf < 4; ++nf)
                    oacc[nf][cf] = MFMA(pa[nf], bv, oacc[nf][cf]);
            }
        }
        __syncthreads();
    }
    #pragma unroll
    for (int r = 0; r < 4; ++r) {
        #pragma unroll
        for (int mk = 1; mk <= 8; mk <<= 1)
            lrun[r] += __shfl_xor(lrun[r], mk);
    }
    if (lr == 0) {
        #pragma unroll
        for (int r = 0; r < 4; ++r) {
            int n = n0 + wave * 16 + lg * 4 + r;
            ml[((size_t)z * BB + b) * NN + n] = make_float2(mrun[r], lrun[r]);
        }
    }
    #pragma unroll
    for (int nf = 0; nf < 4; ++nf) {
        int nbase = n0 + nh * 64 + nf * 16 + lg * 4;
        #pragma unroll
        for (int cf = 0; cf < 4; ++cf) {
            int c = cq * 64 + cf * 16 + lr;
            union { ushort4 u4; unsigned short us[4]; } pk;
            #pragma unroll
            for (int j = 0; j < 4; ++j) {
                __hip_bfloat16 hv = __float2bfloat16(oacc[nf][cf][j]);
                pk.us[j] = *reinterpret_cast<unsigned short*>(&hv);
            }
            *reinterpret_cast<ushort4*>(&opart[((size_t)b * CC + c) * NN + nbase]) = pk.u4;
        }
    }
}

// ---- combine: out[b][c][n] = sum_z o_z*exp(m_z-M) / sum_z l_z*exp(m_z-M) ----
__global__ __launch_bounds__(256) void k_combine(
        const __hip_bfloat16* __restrict__ o0, const __hip_bfloat16* __restrict__ o1,
        const __hip_bfloat16* __restrict__ o2, const __hip_bfloat16* __restrict__ o3,
        const float2* __restrict__ ml, int nsplit, float* __restrict__ out) {
    size_t idx = ((size_t)blockIdx.x * 256 + threadIdx.x) * 4;   // over B*CC*NN
    int n4 = (int)(idx % NN);
    int c  = (int)((idx / NN) % CC);
    int b  = (int)(idx / ((size_t)NN * CC));
    float M[4] = {-1e30f, -1e30f, -1e30f, -1e30f};
    for (int zz = 0; zz < nsplit; ++zz) {
        #pragma unroll
        for (int j = 0; j < 4; ++j)
            M[j] = fmaxf(M[j], ml[((size_t)zz * BB + b) * NN + n4 + j].x);
    }
    float num[4] = {}, den[4] = {};
    for (int zz = 0; zz < nsplit; ++zz) {
        const __hip_bfloat16* op = (zz == 0) ? o0 : (zz == 1) ? o1 : (zz == 2) ? o2 : o3;
        ushort4 u = *reinterpret_cast<const ushort4*>(op + ((size_t)b * CC + c) * NN + n4);
        unsigned short us[4] = {u.x, u.y, u.z, u.w};
        #pragma unroll
        for (int j = 0; j < 4; ++j) {
            float2 v = ml[((size_t)zz * BB + b) * NN + n4 + j];
            float w = __expf(v.x - M[j]);
            num[j] += bf2f(us[j]) * w;
            den[j] += v.y * w;
        }
    }
    f32x4 o;
    #pragma unroll
    for (int j = 0; j < 4; ++j) o[j] = num[j] / den[j];
    *reinterpret_cast<f32x4*>(&out[idx]) = o;
}

extern "C" void kernel_launch(void* const* d_in, const int* in_sizes, int n_in,
                              void* d_out, int out_size, void* d_ws, size_t ws_size,
                              hipStream_t stream) {
    const float* x     = (const float*)d_in[0];
    const float* Wq    = (const float*)d_in[1];
    const float* bq    = (const float*)d_in[2];
    const float* Wk    = (const float*)d_in[3];
    const float* bk    = (const float*)d_in[4];
    const float* Wv    = (const float*)d_in[5];
    const float* bv    = (const float*)d_in[6];
    const float* rel_h = (const float*)d_in[7];
    const float* rel_w = (const float*)d_in[8];
    float* out = (float*)d_out;

    size_t off = 0;
    auto carve = [&](size_t bytes) {
        void* p = (char*)d_ws + off;
        off += (bytes + 255) & ~(size_t)255;
        return p;
    };
    const size_t sz_t = (size_t)BB * NN * CC * 2;   // one 2B plane = 18.87 MB
    _Float16* qt_hi  = (_Float16*)carve(sz_t);
    _Float16* qt_lo  = (_Float16*)carve(sz_t);
    _Float16* kt     = (_Float16*)carve(sz_t);
    __hip_bfloat16* vbuf = (__hip_bfloat16*)carve(sz_t);
    _Float16* relhT = (_Float16*)carve((size_t)HH * CC * 2);
    _Float16* relwT = (_Float16*)carve((size_t)HH * CC * 2);
    _Float16* w     = (_Float16*)carve((size_t)3 * CC * CC * 2);
    float* rhq = (float*)carve((size_t)BB * HH * NN * 4);
    float* rwq = (float*)carve((size_t)BB * HH * NN * 4);
    float2* ml = (float2*)carve((size_t)4 * BB * NN * sizeof(float2));
    __hip_bfloat16* o0 = (__hip_bfloat16*)carve(sz_t);
    __hip_bfloat16* o1 = (__hip_bfloat16*)carve(sz_t);
    if (off > ws_size) return;   // base workspace too small -> visible failure

    __hip_bfloat16* o2 = nullptr;
    __hip_bfloat16* o3 = nullptr;
    int nsplit = 2;
    {
        size_t save = off;
        __hip_bfloat16* p2 = (__hip_bfloat16*)carve(sz_t);
        __hip_bfloat16* p3 = (__hip_bfloat16*)carve(sz_t);
        if (off <= ws_size) { nsplit = 4; o2 = p2; o3 = p3; }
        else { off = save; }
    }
    int tpb = 36 / nsplit;

    k_prep_w<<<dim3(3 * CC * CC / 256), 256, 0, stream>>>(Wq, Wk, Wv, w);
    k_prep_rel<<<dim3(HH * CC / 256), 256, 0, stream>>>(rel_h, rel_w, relhT, relwT);
    k_projqkv<<<dim3(NN / 32, BB), 256, 0, stream>>>(
        x, w, bq, bk, bv, qt_hi, qt_lo, kt, vbuf);
    k_posq<<<dim3(NN / 64, BB), 256, 0, stream>>>(
        qt_hi, qt_lo, relhT, relwT, rhq, rwq);
    k_attn<<<dim3(NN / 128, BB, nsplit), 512, 0, stream>>>(
        qt_hi, kt, rhq, rwq, vbuf, o0, o1, o2, o3, ml, tpb);
    k_combine<<<dim3((size_t)BB * CC * NN / 1024), 256, 0, stream>>>(
        o0, o1, o2, o3, ml, nsplit, out);
}

// Round 20
// 404.585 us; speedup vs baseline: 1.7919x; 1.0995x over previous
//
#include <hip/hip_runtime.h>
#include <hip/hip_bf16.h>

// MHSA: B=16, C=256, H=W=48, N=2304.
// S[b,n,m] = q[b,:,n]·k[b,:,m] + rhq[b][n%48][m] + rwq[b][n/48][m]
// att = softmax_m(S); out[b,c,n] = sum_m v[b,c,m] att[n,m]
// Numerics: attn S q 1-pass f16, defer-max THR=8 (R17/18-proven, 0.0625).
// R20: posq FUSED into projqkv — q hi/lo staged in dead xf LDS (same values,
// same accumulation order as R19's posq -> bit-identical rhq/rwq); qt_lo
// global plane eliminated. v stored via LDS repack -> full-line 64B stores.

#define BB 16
#define CC 256
#define HH 48
#define NN 2304

typedef float f32x4 __attribute__((ext_vector_type(4)));
typedef short bf16x8 __attribute__((ext_vector_type(8)));
typedef _Float16 f16x8 __attribute__((ext_vector_type(8)));

#define MFMA(a, b, c)  __builtin_amdgcn_mfma_f32_16x16x32_bf16((a), (b), (c), 0, 0, 0)
#define MFMAH(a, b, c) __builtin_amdgcn_mfma_f32_16x16x32_f16((a), (b), (c), 0, 0, 0)

__device__ inline bf16x8 ldg8(const __hip_bfloat16* p) {
    return *reinterpret_cast<const bf16x8*>(p);
}
__device__ inline f16x8 ldh8(const _Float16* p) {
    return *reinterpret_cast<const f16x8*>(p);
}
__device__ inline float bf2f(unsigned short v) {
    unsigned u = (unsigned)v << 16;
    float f;
    __builtin_memcpy(&f, &u, 4);
    return f;
}

typedef __attribute__((address_space(3))) unsigned int lds_uint;
typedef const __attribute__((address_space(1))) unsigned int gbl_uint;

__device__ inline void gload_lds16(const void* g, void* l) {
    __builtin_amdgcn_global_load_lds((gbl_uint*)g, (lds_uint*)l, 16, 0, 0);
}

// ---- prep: W -> single f16 plane ([3][256][256]) ----
__global__ __launch_bounds__(256) void k_prep_w(const float* __restrict__ Wq,
        const float* __restrict__ Wk, const float* __restrict__ Wv,
        _Float16* __restrict__ w) {
    int i = blockIdx.x * 256 + threadIdx.x;         // < 3*65536
    int m = i >> 16, j = i & 65535;
    const float* W = (m == 0) ? Wq : ((m == 1) ? Wk : Wv);
    w[i] = (_Float16)W[j];
}

// ---- prep: relhT[h][c] = rel_h[c][h] etc, f16 ----
__global__ __launch_bounds__(256) void k_prep_rel(const float* __restrict__ rel_h,
        const float* __restrict__ rel_w,
        _Float16* __restrict__ relhT, _Float16* __restrict__ relwT) {
    int i = blockIdx.x * 256 + threadIdx.x;         // < 48*256
    int h = i >> 8, c = i & 255;
    relhT[i] = (_Float16)rel_h[c * HH + h];
    relwT[i] = (_Float16)rel_w[c * HH + h];
}

// ---- unified QKV projection + fused pos rank-split (R20) ----
// grid (72, 16); block = 32 n-rows, 4 waves (o-slice 64 each).
// Phases: load x -> xf; split f16 hi/lo -> lds_a (XOR swizzle); q-GEMM
// (2-pass) + q hi/lo -> qlds (in dead xf, swizzled); barrier; pos-GEMM
// (waves split {rh,rw} x {m-tile}, bit-identical to old k_posq); k-GEMM
// (2-pass); v-GEMM (1-pass); barrier; v repack via xf; full-line v stores.
__global__ __launch_bounds__(256) void k_projqkv(
        const float* __restrict__ x,
        const _Float16* __restrict__ w,
        const float* __restrict__ bq, const float* __restrict__ bk, const float* __restrict__ bv,
        const _Float16* __restrict__ relhT, const _Float16* __restrict__ relwT,
        _Float16* __restrict__ qt_hi, _Float16* __restrict__ kt,
        __hip_bfloat16* __restrict__ vbuf,
        float* __restrict__ rhq, float* __restrict__ rwq) {
    __shared__ float xf[32][257];                          // 32.9KB; reused: qlds (32KB), v-repack (20.5KB)
    __shared__ __align__(16) _Float16 lds_a[2][32][256];   // [hi/lo][row][c] 32KB swizzled
    _Float16* qlds = reinterpret_cast<_Float16*>(&xf[0][0]);        // [2][32][256] swizzled
    __hip_bfloat16* vt = reinterpret_cast<__hip_bfloat16*>(&xf[0][0]); // [256][40] padded
    int b = blockIdx.y;
    int n0 = blockIdx.x * 32;
    int t = threadIdx.x;
    int wave = t >> 6, lane = t & 63;
    int lr = lane & 15, lg = lane >> 4;
    int o0 = wave * 64;
    const size_t bN = (size_t)b * NN;

    // load x (coalesced 128B per c-row) into f32 tile
    {
        int nj = t & 31, cg = t >> 5;
        #pragma unroll
        for (int it = 0; it < 32; ++it) {
            int c = it * 8 + cg;
            xf[nj][c] = x[((size_t)b * CC + c) * NN + n0 + nj];
        }
    }
    __syncthreads();
    // split to f16 hi/lo, write swizzled
    {
        int r = t & 31, cg = t >> 5;
        #pragma unroll
        for (int i = 0; i < 32; ++i) {
            int c = cg + 8 * i;
            float v = xf[r][c];
            _Float16 h = (_Float16)v;
            int pc = (((c >> 3) ^ (r & 7)) << 3) | (c & 7);
            lds_a[0][r][pc] = h;
            lds_a[1][r][pc] = (_Float16)(v - (float)h);
        }
    }
    __syncthreads();   // also: xf reads complete -> safe to overwrite as qlds

    // ---- q-GEMM (pj=0, 2-pass) ----
    {
        const _Float16* wp = w;
        f32x4 acc[2][4] = {};
        #pragma unroll
        for (int ks = 0; ks < 8; ++ks) {
            int kk = ks * 32 + lg * 8;
            f16x8 ah[2], al[2];
            #pragma unroll
            for (int nt = 0; nt < 2; ++nt) {
                int row = nt * 16 + lr;
                int ch = ((ks * 4 + lg) ^ (lr & 7)) * 8;
                ah[nt] = *reinterpret_cast<const f16x8*>(&lds_a[0][row][ch]);
                al[nt] = *reinterpret_cast<const f16x8*>(&lds_a[1][row][ch]);
            }
            #pragma unroll
            for (int ot = 0; ot < 4; ++ot) {
                int rowB = o0 + ot * 16 + lr;
                f16x8 bh = ldh8(wp + rowB * CC + kk);
                #pragma unroll
                for (int nt = 0; nt < 2; ++nt) {
                    acc[nt][ot] = MFMAH(ah[nt], bh, acc[nt][ot]);
                    acc[nt][ot] = MFMAH(al[nt], bh, acc[nt][ot]);
                }
            }
        }
        #pragma unroll
        for (int ot = 0; ot < 4; ++ot) {
            int o = o0 + ot * 16 + lr;
            float bb = bq[o];
            #pragma unroll
            for (int nt = 0; nt < 2; ++nt) {
                #pragma unroll
                for (int r = 0; r < 4; ++r) {
                    int nl = nt * 16 + lg * 4 + r;
                    float y = acc[nt][ot][r] + bb;
                    _Float16 h = (_Float16)y;
                    _Float16 lo = (_Float16)(y - (float)h);
                    qt_hi[(bN + n0 + nl) * CC + o] = h;
                    int pc = (((o >> 3) ^ (nl & 7)) << 3) | (o & 7);
                    qlds[nl * 256 + pc] = h;
                    qlds[8192 + nl * 256 + pc] = lo;
                }
            }
        }
    }
    __syncthreads();   // qlds complete (all waves)

    // ---- fused pos rank-split (bit-identical to old k_posq) ----
    // wave 0,1 -> rh (m-tile 0,1); wave 2,3 -> rw (m-tile 0,1)
    {
        int rel_sel = wave >> 1, mtile = wave & 1;
        const _Float16* rel = rel_sel ? relwT : relhT;
        float* rout = rel_sel ? rwq : rhq;
        int brow = mtile * 16 + lr;
        f32x4 pacc[3] = {};
        #pragma unroll
        for (int ks = 0; ks < 8; ++ks) {
            int kk = ks * 32 + lg * 8;
            int bch = ((ks * 4 + lg) ^ (brow & 7)) * 8;
            f16x8 bh = *reinterpret_cast<const f16x8*>(&qlds[brow * 256 + bch]);
            f16x8 bl = *reinterpret_cast<const f16x8*>(&qlds[8192 + brow * 256 + bch]);
            #pragma unroll
            for (int ht = 0; ht < 3; ++ht) {
                f16x8 a = ldh8(rel + (ht * 16 + lr) * CC + kk);
                pacc[ht] = MFMAH(a, bh, pacc[ht]);
                pacc[ht] = MFMAH(a, bl, pacc[ht]);
            }
        }
        #pragma unroll
        for (int ht = 0; ht < 3; ++ht) {
            #pragma unroll
            for (int r = 0; r < 4; ++r) {
                int h = ht * 16 + lg * 4 + r;
                int m = n0 + mtile * 16 + lr;
                rout[((size_t)b * HH + h) * NN + m] = pacc[ht][r];
            }
        }
    }

    // ---- k-GEMM (pj=1, 2-pass) ----
    {
        const _Float16* wp = w + 65536;
        f32x4 acc[2][4] = {};
        #pragma unroll
        for (int ks = 0; ks < 8; ++ks) {
            int kk = ks * 32 + lg * 8;
            f16x8 ah[2], al[2];
            #pragma unroll
            for (int nt = 0; nt < 2; ++nt) {
                int row = nt * 16 + lr;
                int ch = ((ks * 4 + lg) ^ (lr & 7)) * 8;
                ah[nt] = *reinterpret_cast<const f16x8*>(&lds_a[0][row][ch]);
                al[nt] = *reinterpret_cast<const f16x8*>(&lds_a[1][row][ch]);
            }
            #pragma unroll
            for (int ot = 0; ot < 4; ++ot) {
                int rowB = o0 + ot * 16 + lr;
                f16x8 bh = ldh8(wp + rowB * CC + kk);
                #pragma unroll
                for (int nt = 0; nt < 2; ++nt) {
                    acc[nt][ot] = MFMAH(ah[nt], bh, acc[nt][ot]);
                    acc[nt][ot] = MFMAH(al[nt], bh, acc[nt][ot]);
                }
            }
        }
        #pragma unroll
        for (int ot = 0; ot < 4; ++ot) {
            int o = o0 + ot * 16 + lr;
            float bb = bk[o];
            #pragma unroll
            for (int nt = 0; nt < 2; ++nt) {
                #pragma unroll
                for (int r = 0; r < 4; ++r) {
                    int nl = nt * 16 + lg * 4 + r;
                    kt[(bN + n0 + nl) * CC + o] = (_Float16)(acc[nt][ot][r] + bb);
                }
            }
        }
    }

    // ---- v-GEMM (pj=2, 1-pass) + full-line store via LDS repack ----
    {
        const _Float16* wp = w + 2 * 65536;
        f32x4 acc[2][4] = {};
        #pragma unroll
        for (int ks = 0; ks < 8; ++ks) {
            int kk = ks * 32 + lg * 8;
            f16x8 ah[2];
            #pragma unroll
            for (int nt = 0; nt < 2; ++nt) {
                int row = nt * 16 + lr;
                int ch = ((ks * 4 + lg) ^ (lr & 7)) * 8;
                ah[nt] = *reinterpret_cast<const f16x8*>(&lds_a[0][row][ch]);
            }
            #pragma unroll
            for (int ot = 0; ot < 4; ++ot) {
                int rowB = o0 + ot * 16 + lr;
                f16x8 bh = ldh8(wp + rowB * CC + kk);
                #pragma unroll
                for (int nt = 0; nt < 2; ++nt)
                    acc[nt][ot] = MFMAH(ah[nt], bh, acc[nt][ot]);
            }
        }
        __syncthreads();   // all waves past pos-phase reads of qlds (xf reuse)
        #pragma unroll
        for (int ot = 0; ot < 4; ++ot) {
            int o = o0 + ot * 16 + lr;
            float bb = bv[o];
            #pragma unroll
            for (int nt = 0; nt < 2; ++nt) {
                #pragma unroll
                for (int r = 0; r < 4; ++r) {
                    int nl = nt * 16 + lg * 4 + r;
                    vt[o * 40 + nl] = __float2bfloat16(acc[nt][ot][r] + bb);
                }
            }
        }
        __syncthreads();
        // thread t stores c-row t: 64B = one full cache line
        #pragma unroll
        for (int j = 0; j < 4; ++j) {
            bf16x8 vv = *reinterpret_cast<const bf16x8*>(&vt[t * 40 + j * 8]);
            *reinterpret_cast<bf16x8*>(&vbuf[((size_t)b * CC + t) * NN + n0 + j * 8]) = vv;
        }
    }
}

// ---- flash attention, split-KV, shuffle-free steady-state softmax (R18) ----
__global__ __launch_bounds__(512, 2) void k_attn(
        const _Float16* __restrict__ qt_hi,
        const _Float16* __restrict__ kt,
        const float* __restrict__ rhq, const float* __restrict__ rwq,
        const __hip_bfloat16* __restrict__ vbuf,
        __hip_bfloat16* __restrict__ o0, __hip_bfloat16* __restrict__ o1,
        __hip_bfloat16* __restrict__ o2, __hip_bfloat16* __restrict__ o3,
        float2* __restrict__ ml, int tpb) {
    __shared__ __align__(16) _Float16 lds_k[2][64][128];          // [slice][row][k] 32KB
    __shared__ __align__(16) __hip_bfloat16 lds_v[256][64];       // [c][m] 32KB (swizzled)
    __shared__ __align__(16) __hip_bfloat16 lds_p[128][64];       // shared P tile 16KB (swizzled)
    float* lds_scale = reinterpret_cast<float*>(&lds_k[1][0][0]);
    int*   lds_flag  = reinterpret_cast<int*>(lds_scale + 128);   // [8]
    int b = blockIdx.y;
    int n0 = blockIdx.x * 128;
    int z = blockIdx.z;
    int t0 = z * tpb, t_end = t0 + tpb;
    __hip_bfloat16* opart = (z == 0) ? o0 : (z == 1) ? o1 : (z == 2) ? o2 : o3;
    int wave = threadIdx.x >> 6, lane = threadIdx.x & 63;
    int lr = lane & 15, lg = lane >> 4;
    int rowA = n0 + wave * 16 + lr;
    const size_t bN = (size_t)b * NN;

    f16x8 qh[8];
    #pragma unroll
    for (int ks = 0; ks < 8; ++ks) {
        int kk = ks * 32 + lg * 8;
        qh[ks] = ldh8(qt_hi + (bN + rowA) * CC + kk);
    }
    int hn[4], wn[4];
    #pragma unroll
    for (int r = 0; r < 4; ++r) {
        int n = n0 + wave * 16 + lg * 4 + r;
        hn[r] = n % HH;
        wn[r] = n / HH;
    }
    const float* rhq_b = rhq + (size_t)b * HH * NN;
    const float* rwq_b = rwq + (size_t)b * HH * NN;

    int nh = wave >> 2;                 // n-half
    int cq = wave & 3;                  // c-quarter
    f32x4 oacc[4][4] = {};              // [nf][cf]
    float mrun[4] = {-1e30f, -1e30f, -1e30f, -1e30f};
    float lrun[4] = {0.f, 0.f, 0.f, 0.f};   // per-lane partial (epilogue-reduced)

    int krin = lane >> 4, kch = lane & 15;
    auto STAGE_K = [&](int buf, int m0s, int k0) {
        #pragma unroll
        for (int j = 0; j < 2; ++j) {
            int lrow = wave * 8 + j * 4;
            int grow = lrow + krin;
            gload_lds16(kt + (bN + m0s + grow) * CC + k0 + ((kch ^ (grow & 7)) * 8),
                        &lds_k[buf][lrow][0]);
        }
    };
    int srl = lane >> 3;
    int sch = ((lane & 7) ^ srl) * 8;
    auto STAGE_V = [&](int half, int m0s) {
        #pragma unroll
        for (int j = 0; j < 2; ++j) {
            int lrow = half * 128 + wave * 16 + j * 8;
            int crow = lrow + srl;
            gload_lds16(vbuf + ((size_t)b * CC + crow) * NN + m0s + sch, &lds_v[lrow][0]);
        }
    };

    STAGE_K(0, t0 * 64, 0);
    __syncthreads();

    for (int t = t0; t < t_end; ++t) {
        int m0 = t * 64;
        float padd[4][4];
        #pragma unroll
        for (int mt = 0; mt < 4; ++mt) {
            int m = m0 + mt * 16 + lr;
            #pragma unroll
            for (int r = 0; r < 4; ++r)
                padd[mt][r] = rhq_b[(size_t)hn[r] * NN + m] + rwq_b[(size_t)wn[r] * NN + m];
        }
        f32x4 sacc[4] = {};
        #pragma unroll
        for (int s = 0; s < 2; ++s) {
            if (s == 0) {
                STAGE_K(1, m0, 128);
                STAGE_V(0, m0);
            } else {
                int mn = (t + 1 < t_end) ? (t + 1) * 64 : t0 * 64;
                STAGE_K(0, mn, 0);
                STAGE_V(1, m0);
            }
            #pragma unroll
            for (int ks = 0; ks < 4; ++ks) {
                #pragma unroll
                for (int mt = 0; mt < 4; ++mt) {
                    int row = mt * 16 + lr;
                    int ch = ((ks * 4 + lg) ^ (lr & 7)) * 8;
                    f16x8 bh = *reinterpret_cast<const f16x8*>(&lds_k[s][row][ch]);
                    sacc[mt] = MFMAH(qh[s * 4 + ks], bh, sacc[mt]);
                }
            }
            __syncthreads();
        }
        #pragma unroll
        for (int mt = 0; mt < 4; ++mt)
            #pragma unroll
            for (int r = 0; r < 4; ++r)
                sacc[mt][r] += padd[mt][r];
        bool lane_need = false;
        #pragma unroll
        for (int mt = 0; mt < 4; ++mt)
            #pragma unroll
            for (int r = 0; r < 4; ++r)
                lane_need |= (sacc[mt][r] > mrun[r] + 8.0f);
        bool wave_need = __any(lane_need);
        float scl_r[4] = {1.f, 1.f, 1.f, 1.f};
        if (wave_need) {
            #pragma unroll
            for (int r = 0; r < 4; ++r) {
                float smax = fmaxf(fmaxf(sacc[0][r], sacc[1][r]),
                                   fmaxf(sacc[2][r], sacc[3][r]));
                #pragma unroll
                for (int mk = 1; mk <= 8; mk <<= 1)
                    smax = fmaxf(smax, __shfl_xor(smax, mk));
                float mnew = fmaxf(mrun[r], smax);
                scl_r[r] = __expf(mrun[r] - mnew);
                mrun[r] = mnew;
                lrun[r] *= scl_r[r];
            }
        }
        #pragma unroll
        for (int r = 0; r < 4; ++r) {
            float rsum = 0.f;
            #pragma unroll
            for (int mt = 0; mt < 4; ++mt) {
                float p = __expf(sacc[mt][r] - mrun[r]);
                sacc[mt][r] = p;
                rsum += p;
            }
            lrun[r] += rsum;
        }
        #pragma unroll
        for (int mt = 0; mt < 4; ++mt) {
            #pragma unroll
            for (int r = 0; r < 4; ++r) {
                int prow = wave * 16 + lg * 4 + r;
                int pcol = mt * 16 + lr;
                int pcol_s = (((pcol >> 3) ^ (prow & 7)) << 3) | (pcol & 7);
                lds_p[prow][pcol_s] = __float2bfloat16(sacc[mt][r]);
            }
        }
        if (lr == 0) {
            #pragma unroll
            for (int r = 0; r < 4; ++r)
                lds_scale[wave * 16 + lg * 4 + r] = scl_r[r];
        }
        if (lane == 0) lds_flag[wave] = wave_need ? 1 : 0;
        __syncthreads();
        int4 f0 = *reinterpret_cast<const int4*>(&lds_flag[0]);
        int4 f1 = *reinterpret_cast<const int4*>(&lds_flag[4]);
        bool do_scale = (f0.x | f0.y | f0.z | f0.w | f1.x | f1.y | f1.z | f1.w) != 0;
        if (do_scale) {
            #pragma unroll
            for (int nf = 0; nf < 4; ++nf) {
                f32x4 s4 = *reinterpret_cast<const f32x4*>(&lds_scale[nh * 64 + nf * 16 + lg * 4]);
                #pragma unroll
                for (int cf = 0; cf < 4; ++cf)
                    oacc[nf][cf] *= s4;
            }
        }
        #pragma unroll
        for (int ks2 = 0; ks2 < 2; ++ks2) {
            bf16x8 pa[4];
            #pragma unroll
            for (int nf = 0; nf < 4; ++nf) {
                int prow = nh * 64 + nf * 16 + lr;
                int pch = ((ks2 * 4 + lg) ^ (lr & 7)) * 8;
                pa[nf] = *reinterpret_cast<const bf16x8*>(&lds_p[prow][pch]);
            }
            #pragma unroll
            for (int cf = 0; cf < 4; ++cf) {
                int vrow = cq * 64 + cf * 16 + lr;
                int vch = ((ks2 * 4 + lg) ^ (lr & 7)) * 8;
                bf16x8 bv = *reinterpret_cast<const bf16x8*>(&lds_v[vrow][vch]);
                #pragma unroll
                for (int nf = 0; nf < 4; ++nf)
                    oacc[nf][cf] = MFMA(pa[nf], bv, oacc[nf][cf]);
            }
        }
        __syncthreads();
    }
    #pragma unroll
    for (int r = 0; r < 4; ++r) {
        #pragma unroll
        for (int mk = 1; mk <= 8; mk <<= 1)
            lrun[r] += __shfl_xor(lrun[r], mk);
    }
    if (lr == 0) {
        #pragma unroll
        for (int r = 0; r < 4; ++r) {
            int n = n0 + wave * 16 + lg * 4 + r;
            ml[((size_t)z * BB + b) * NN + n] = make_float2(mrun[r], lrun[r]);
        }
    }
    #pragma unroll
    for (int nf = 0; nf < 4; ++nf) {
        int nbase = n0 + nh * 64 + nf * 16 + lg * 4;
        #pragma unroll
        for (int cf = 0; cf < 4; ++cf) {
            int c = cq * 64 + cf * 16 + lr;
            union { ushort4 u4; unsigned short us[4]; } pk;
            #pragma unroll
            for (int j = 0; j < 4; ++j) {
                __hip_bfloat16 hv = __float2bfloat16(oacc[nf][cf][j]);
                pk.us[j] = *reinterpret_cast<unsigned short*>(&hv);
            }
            *reinterpret_cast<ushort4*>(&opart[((size_t)b * CC + c) * NN + nbase]) = pk.u4;
        }
    }
}

// ---- combine: out[b][c][n] = sum_z o_z*exp(m_z-M) / sum_z l_z*exp(m_z-M) ----
__global__ __launch_bounds__(256) void k_combine(
        const __hip_bfloat16* __restrict__ o0, const __hip_bfloat16* __restrict__ o1,
        const __hip_bfloat16* __restrict__ o2, const __hip_bfloat16* __restrict__ o3,
        const float2* __restrict__ ml, int nsplit, float* __restrict__ out) {
    size_t idx = ((size_t)blockIdx.x * 256 + threadIdx.x) * 4;   // over B*CC*NN
    int n4 = (int)(idx % NN);
    int c  = (int)((idx / NN) % CC);
    int b  = (int)(idx / ((size_t)NN * CC));
    float M[4] = {-1e30f, -1e30f, -1e30f, -1e30f};
    for (int zz = 0; zz < nsplit; ++zz) {
        #pragma unroll
        for (int j = 0; j < 4; ++j)
            M[j] = fmaxf(M[j], ml[((size_t)zz * BB + b) * NN + n4 + j].x);
    }
    float num[4] = {}, den[4] = {};
    for (int zz = 0; zz < nsplit; ++zz) {
        const __hip_bfloat16* op = (zz == 0) ? o0 : (zz == 1) ? o1 : (zz == 2) ? o2 : o3;
        ushort4 u = *reinterpret_cast<const ushort4*>(op + ((size_t)b * CC + c) * NN + n4);
        unsigned short us[4] = {u.x, u.y, u.z, u.w};
        #pragma unroll
        for (int j = 0; j < 4; ++j) {
            float2 v = ml[((size_t)zz * BB + b) * NN + n4 + j];
            float w = __expf(v.x - M[j]);
            num[j] += bf2f(us[j]) * w;
            den[j] += v.y * w;
        }
    }
    f32x4 o;
    #pragma unroll
    for (int j = 0; j < 4; ++j) o[j] = num[j] / den[j];
    *reinterpret_cast<f32x4*>(&out[idx]) = o;
}

extern "C" void kernel_launch(void* const* d_in, const int* in_sizes, int n_in,
                              void* d_out, int out_size, void* d_ws, size_t ws_size,
                              hipStream_t stream) {
    const float* x     = (const float*)d_in[0];
    const float* Wq    = (const float*)d_in[1];
    const float* bq    = (const float*)d_in[2];
    const float* Wk    = (const float*)d_in[3];
    const float* bk    = (const float*)d_in[4];
    const float* Wv    = (const float*)d_in[5];
    const float* bv    = (const float*)d_in[6];
    const float* rel_h = (const float*)d_in[7];
    const float* rel_w = (const float*)d_in[8];
    float* out = (float*)d_out;

    size_t off = 0;
    auto carve = [&](size_t bytes) {
        void* p = (char*)d_ws + off;
        off += (bytes + 255) & ~(size_t)255;
        return p;
    };
    const size_t sz_t = (size_t)BB * NN * CC * 2;   // one 2B plane = 18.87 MB
    _Float16* qt_hi  = (_Float16*)carve(sz_t);
    _Float16* kt     = (_Float16*)carve(sz_t);
    __hip_bfloat16* vbuf = (__hip_bfloat16*)carve(sz_t);
    _Float16* relhT = (_Float16*)carve((size_t)HH * CC * 2);
    _Float16* relwT = (_Float16*)carve((size_t)HH * CC * 2);
    _Float16* w     = (_Float16*)carve((size_t)3 * CC * CC * 2);
    float* rhq = (float*)carve((size_t)BB * HH * NN * 4);
    float* rwq = (float*)carve((size_t)BB * HH * NN * 4);
    float2* ml = (float2*)carve((size_t)4 * BB * NN * sizeof(float2));
    __hip_bfloat16* o0 = (__hip_bfloat16*)carve(sz_t);
    __hip_bfloat16* o1 = (__hip_bfloat16*)carve(sz_t);
    if (off > ws_size) return;   // base workspace too small -> visible failure

    __hip_bfloat16* o2 = nullptr;
    __hip_bfloat16* o3 = nullptr;
    int nsplit = 2;
    {
        size_t save = off;
        __hip_bfloat16* p2 = (__hip_bfloat16*)carve(sz_t);
        __hip_bfloat16* p3 = (__hip_bfloat16*)carve(sz_t);
        if (off <= ws_size) { nsplit = 4; o2 = p2; o3 = p3; }
        else { off = save; }
    }
    int tpb = 36 / nsplit;

    k_prep_w<<<dim3(3 * CC * CC / 256), 256, 0, stream>>>(Wq, Wk, Wv, w);
    k_prep_rel<<<dim3(HH * CC / 256), 256, 0, stream>>>(rel_h, rel_w, relhT, relwT);
    k_projqkv<<<dim3(NN / 32, BB), 256, 0, stream>>>(
        x, w, bq, bk, bv, relhT, relwT, qt_hi, kt, vbuf, rhq, rwq);
    k_attn<<<dim3(NN / 128, BB, nsplit), 512, 0, stream>>>(
        qt_hi, kt, rhq, rwq, vbuf, o0, o1, o2, o3, ml, tpb);
    k_combine<<<dim3((size_t)BB * CC * NN / 1024), 256, 0, stream>>>(
        o0, o1, o2, o3, ml, nsplit, out);
}